// Round 1
// baseline (788.798 us; speedup 1.0000x reference)
//
#include <hip/hip_runtime.h>
#include <hip/hip_bf16.h>

#define N_NODES 50000
#define N_EDGES 300000
#define HIDDEN 256
#define ZDIM 128
#define NLAYERS 3
#define NGRAPHS 16
#define EPS 1e-5f

// ---- fp32 param region offsets (floats) ----
#define OFF_POS    0
#define OFF_WIN    150000
#define OFF_BIN    150768
#define OFF_GIN    151024
#define OFF_BEIN   151280
#define OFF_CONVW  151536
#define OFF_CONVB  348144
#define OFF_GNG    348912
#define OFF_GNB    349680
#define OFF_WO1    350448
#define OFF_BO1    415984
#define OFF_GO     416240
#define OFF_BEO    416496
#define OFF_WO2    416752
#define OFF_BO2    449520
#define PARAMS_TOTAL 449648

__device__ inline float wave_reduce_sum(float v){
#pragma unroll
  for (int off = 32; off; off >>= 1) v += __shfl_xor(v, off);
  return v;
}

// ---- dtype detection: flag=1 -> inputs stored fp32, flag=0 -> bf16 ----
__global__ void k_detect(const unsigned short* __restrict__ w_in, int* __restrict__ flag){
  __shared__ int sf;
  int tid = threadIdx.x;
  if (tid == 0) sf = 0;
  __syncthreads();
  for (int i = tid; i < 768; i += 256){
    int e = (w_in[i] >> 7) & 0xff;          // bf16 exponent field
    if (e >= 148) atomicOr(&sf, 1);         // |v| >= 2^20: impossible for real bf16 weights
  }
  __syncthreads();
  if (tid == 0) *flag = sf;
}

struct CvtArgs { const void* src[15]; int n[15]; int off[15]; };

__global__ void k_convert(CvtArgs a, float* __restrict__ params, const int* __restrict__ flag){
  const bool isf32 = (*flag != 0);
  int stride = gridDim.x * blockDim.x;
  int t0 = blockIdx.x * blockDim.x + threadIdx.x;
  for (int s = 0; s < 15; ++s){
    const void* src = a.src[s];
    int n = a.n[s];
    float* dst = params + a.off[s];
    if (isf32){
      const float* f = (const float*)src;
      for (int i = t0; i < n; i += stride) dst[i] = f[i];
    } else {
      const unsigned short* u = (const unsigned short*)src;
      for (int i = t0; i < n; i += stride){
        unsigned int w = ((unsigned int)u[i]) << 16;
        dst[i] = __uint_as_float(w);
      }
    }
  }
}

__global__ void k_init(int* __restrict__ deg, int* __restrict__ fill,
                       float* __restrict__ pooled, float* __restrict__ counts){
  int i = blockIdx.x * blockDim.x + threadIdx.x;
  if (i < N_NODES){ deg[i] = 1; fill[i] = 0; }       // self-loop contributes 1
  if (i < NGRAPHS * 256) pooled[i] = 0.f;
  if (i < NGRAPHS) counts[i] = 0.f;
}

__global__ void k_deg(const int* __restrict__ dst, int* __restrict__ deg){
  int e = blockIdx.x * blockDim.x + threadIdx.x;
  if (e < N_EDGES) atomicAdd(&deg[dst[e]], 1);
}

__global__ void k_dinv(const int* __restrict__ deg, float* __restrict__ dinv){
  int i = blockIdx.x * blockDim.x + threadIdx.x;
  if (i < N_NODES) dinv[i] = rsqrtf((float)deg[i]);
}

// exclusive scan of deg -> row_start, single block of 256, 196 elems/thread serial
#define SCHUNK 196
__global__ __launch_bounds__(256) void k_scan(const int* __restrict__ deg, int* __restrict__ row_start){
  __shared__ int ssum[256];
  int tid = threadIdx.x;
  int beg = tid * SCHUNK;
  int end = min(beg + SCHUNK, N_NODES);
  int s = 0;
  for (int i = beg; i < end; ++i) s += deg[i];
  ssum[tid] = s;
  __syncthreads();
#pragma unroll
  for (int off = 1; off < 256; off <<= 1){
    int v = 0;
    if (tid >= off) v = ssum[tid - off];
    __syncthreads();
    ssum[tid] += v;
    __syncthreads();
  }
  int incl = ssum[tid];
  int run = incl - s;                       // exclusive offset
  for (int i = beg; i < end; ++i){ row_start[i] = run; run += deg[i]; }
  if (tid == 255) row_start[N_NODES] = incl;
}

__global__ void k_fill(const int* __restrict__ src, const int* __restrict__ dst,
                       const int* __restrict__ row_start, int* __restrict__ fill,
                       const float* __restrict__ dinv,
                       int* __restrict__ csr_src, float* __restrict__ csr_w){
  int t = blockIdx.x * blockDim.x + threadIdx.x;
  if (t >= N_EDGES + N_NODES) return;
  int s, d;
  if (t < N_EDGES){ s = src[t]; d = dst[t]; }
  else            { s = t - N_EDGES; d = s; }      // self loops
  int pos = row_start[d] + atomicAdd(&fill[d], 1);
  csr_src[pos] = s;
  csr_w[pos] = dinv[s] * dinv[d];
}

// input projection: Linear(3,256) -> ReLU -> GroupNorm(1,256). one wave per node.
__global__ __launch_bounds__(256) void k_input_proj(const float* __restrict__ params, float* __restrict__ x){
  int lane = threadIdx.x & 63;
  int node = (blockIdx.x << 2) + (threadIdx.x >> 6);
  if (node >= N_NODES) return;
  const float* pos = params + OFF_POS + node * 3;
  float px = pos[0], py = pos[1], pz = pos[2];
  int c = lane * 4;
  const float* w0 = params + OFF_WIN;
  float v[4];
#pragma unroll
  for (int j = 0; j < 4; ++j){
    float t = params[OFF_BIN + c + j];
    t = fmaf(px, w0[c + j], t);
    t = fmaf(py, w0[256 + c + j], t);
    t = fmaf(pz, w0[512 + c + j], t);
    v[j] = fmaxf(t, 0.f);
  }
  float s  = v[0] + v[1] + v[2] + v[3];
  float ss = v[0]*v[0] + v[1]*v[1] + v[2]*v[2] + v[3]*v[3];
  s = wave_reduce_sum(s); ss = wave_reduce_sum(ss);
  float mean = s * (1.f/256.f);
  float var  = ss * (1.f/256.f) - mean * mean;
  float inv  = rsqrtf(var + EPS);
  float4 o;
  o.x = (v[0]-mean)*inv*params[OFF_GIN+c+0] + params[OFF_BEIN+c+0];
  o.y = (v[1]-mean)*inv*params[OFF_GIN+c+1] + params[OFF_BEIN+c+1];
  o.z = (v[2]-mean)*inv*params[OFF_GIN+c+2] + params[OFF_BEIN+c+2];
  o.w = (v[3]-mean)*inv*params[OFF_GIN+c+3] + params[OFF_BEIN+c+3];
  *(float4*)(x + node * 256 + c) = o;
}

// fp32 GEMM: C(Mx256) = A(Mx256) @ B(256x256). BM=128 BN=64 BK=16, 8x4/thread.
#define BM 128
#define BN 64
#define BK 16
__global__ __launch_bounds__(256) void k_gemm(const float* __restrict__ A, const float* __restrict__ B,
                                              float* __restrict__ C, int M){
  __shared__ float As[BK][BM + 4];
  __shared__ float Bs[BK][BN];
  int tid = threadIdx.x;
  int row0 = blockIdx.y * BM, col0 = blockIdx.x * BN;
  int tx = tid & 15, ty = tid >> 4;
  int arow = tid >> 1;
  int akoff = (tid & 1) * 8;
  int bkk = tid >> 4;
  int bcol = (tid & 15) * 4;
  float acc[8][4] = {};
  for (int k0 = 0; k0 < 256; k0 += BK){
    int gr = row0 + arow;
    float4 a0 = {0,0,0,0}, a1 = {0,0,0,0};
    if (gr < M){
      const float* ap = A + gr * 256 + k0 + akoff;
      a0 = *(const float4*)ap;
      a1 = *(const float4*)(ap + 4);
    }
    float4 bv = *(const float4*)(B + (k0 + bkk) * 256 + col0 + bcol);
    __syncthreads();
    As[akoff+0][arow] = a0.x; As[akoff+1][arow] = a0.y;
    As[akoff+2][arow] = a0.z; As[akoff+3][arow] = a0.w;
    As[akoff+4][arow] = a1.x; As[akoff+5][arow] = a1.y;
    As[akoff+6][arow] = a1.z; As[akoff+7][arow] = a1.w;
    *(float4*)&Bs[bkk][bcol] = bv;
    __syncthreads();
#pragma unroll
    for (int kk = 0; kk < BK; ++kk){
      float4 b4 = *(float4*)&Bs[kk][tx * 4];
      float ra[8];
#pragma unroll
      for (int i = 0; i < 8; ++i) ra[i] = As[kk][ty * 8 + i];
#pragma unroll
      for (int i = 0; i < 8; ++i){
        acc[i][0] = fmaf(ra[i], b4.x, acc[i][0]);
        acc[i][1] = fmaf(ra[i], b4.y, acc[i][1]);
        acc[i][2] = fmaf(ra[i], b4.z, acc[i][2]);
        acc[i][3] = fmaf(ra[i], b4.w, acc[i][3]);
      }
    }
  }
#pragma unroll
  for (int i = 0; i < 8; ++i){
    int r = row0 + ty * 8 + i;
    if (r < M){
      float4 v = {acc[i][0], acc[i][1], acc[i][2], acc[i][3]};
      *(float4*)(C + r * 256 + col0 + tx * 4) = v;
    }
  }
}

// aggregate over CSR + bias + GroupNorm + ReLU + residual (in-place x). one wave per node.
__global__ __launch_bounds__(256) void k_agg_norm(const float* __restrict__ h, float* __restrict__ x,
    const int* __restrict__ row_start, const int* __restrict__ csr_src, const float* __restrict__ csr_w,
    const float* __restrict__ params, int layer){
  int lane = threadIdx.x & 63;
  int node = (blockIdx.x << 2) + (threadIdx.x >> 6);
  if (node >= N_NODES) return;
  int c = lane * 4;
  float a0 = 0.f, a1 = 0.f, a2 = 0.f, a3 = 0.f;
  int p0 = row_start[node], p1 = row_start[node + 1];
  for (int p = p0; p < p1; ++p){
    int sidx = csr_src[p];
    float w = csr_w[p];
    float4 hv = *(const float4*)(h + sidx * 256 + c);
    a0 = fmaf(w, hv.x, a0); a1 = fmaf(w, hv.y, a1);
    a2 = fmaf(w, hv.z, a2); a3 = fmaf(w, hv.w, a3);
  }
  const float* cb = params + OFF_CONVB + layer * 256;
  float v[4] = { a0 + cb[c], a1 + cb[c+1], a2 + cb[c+2], a3 + cb[c+3] };
  float s  = v[0] + v[1] + v[2] + v[3];
  float ss = v[0]*v[0] + v[1]*v[1] + v[2]*v[2] + v[3]*v[3];
  s = wave_reduce_sum(s); ss = wave_reduce_sum(ss);
  float mean = s * (1.f/256.f);
  float var  = ss * (1.f/256.f) - mean * mean;
  float inv  = rsqrtf(var + EPS);
  const float* g = params + OFF_GNG + layer * 256;
  const float* b = params + OFF_GNB + layer * 256;
  float4 xo = *(float4*)(x + node * 256 + c);
  float4 o;
  o.x = fmaxf((v[0]-mean)*inv*g[c+0] + b[c+0], 0.f) + xo.x;
  o.y = fmaxf((v[1]-mean)*inv*g[c+1] + b[c+1], 0.f) + xo.y;
  o.z = fmaxf((v[2]-mean)*inv*g[c+2] + b[c+2], 0.f) + xo.z;
  o.w = fmaxf((v[3]-mean)*inv*g[c+3] + b[c+3], 0.f) + xo.w;
  *(float4*)(x + node * 256 + c) = o;
}

__global__ __launch_bounds__(256) void k_pool(const float* __restrict__ x, const int* __restrict__ batch,
                                              float* __restrict__ pooled, float* __restrict__ counts){
  __shared__ float lacc[NGRAPHS * 256];
  __shared__ int lcnt[NGRAPHS];
  int tid = threadIdx.x;
#pragma unroll
  for (int g = 0; g < NGRAPHS; ++g) lacc[g * 256 + tid] = 0.f;
  if (tid < NGRAPHS) lcnt[tid] = 0;
  __syncthreads();
  int base = blockIdx.x * 256;
  for (int j = 0; j < 256; ++j){
    int i = base + j;
    if (i >= N_NODES) break;                 // uniform across block
    int g = batch[i];
    lacc[g * 256 + tid] += x[i * 256 + tid];
    if (tid == 0) lcnt[g]++;
  }
  __syncthreads();
#pragma unroll
  for (int g = 0; g < NGRAPHS; ++g) atomicAdd(&pooled[g * 256 + tid], lacc[g * 256 + tid]);
  if (tid < NGRAPHS && lcnt[tid]) atomicAdd(&counts[tid], (float)lcnt[tid]);
}

__global__ __launch_bounds__(256) void k_head(const float* __restrict__ pooled, const float* __restrict__ counts,
    const float* __restrict__ params, void* __restrict__ out, const int* __restrict__ flag){
  __shared__ float m[256];
  __shared__ float hh[256];
  __shared__ float red[2][4];
  int g = blockIdx.x, tid = threadIdx.x;
  float cnt = fmaxf(counts[g], 1.f);
  m[tid] = pooled[g * 256 + tid] / cnt;
  __syncthreads();
  const float* W1 = params + OFF_WO1;
  float acc = params[OFF_BO1 + tid];
  for (int k = 0; k < 256; ++k) acc = fmaf(m[k], W1[k * 256 + tid], acc);
  acc = fmaxf(acc, 0.f);
  float s = wave_reduce_sum(acc), ss = wave_reduce_sum(acc * acc);
  int wv = tid >> 6, lane = tid & 63;
  if (lane == 0){ red[0][wv] = s; red[1][wv] = ss; }
  __syncthreads();
  float S  = red[0][0] + red[0][1] + red[0][2] + red[0][3];
  float SS = red[1][0] + red[1][1] + red[1][2] + red[1][3];
  float mean = S * (1.f/256.f);
  float var  = SS * (1.f/256.f) - mean * mean;
  float inv  = rsqrtf(var + EPS);
  float hn = (acc - mean) * inv * params[OFF_GO + tid] + params[OFF_BEO + tid];
  hh[tid] = hn;
  __syncthreads();
  if (tid < ZDIM){
    const float* W2 = params + OFF_WO2;
    float o = params[OFF_BO2 + tid];
    for (int k = 0; k < 256; ++k) o = fmaf(hh[k], W2[k * 128 + tid], o);
    if (*flag) ((float*)out)[g * 128 + tid] = o;
    else       ((__hip_bfloat16*)out)[g * 128 + tid] = __float2bfloat16(o);
  }
}

extern "C" void kernel_launch(void* const* d_in, const int* in_sizes, int n_in,
                              void* d_out, int out_size, void* d_ws, size_t ws_size,
                              hipStream_t stream){
  // ---- workspace layout ----
  size_t o = 0;
  auto alloc = [&](size_t bytes)->size_t{ size_t r = o; o = (o + bytes + 255) & ~(size_t)255; return r; };
  size_t off_flag   = alloc(4);
  size_t off_deg    = alloc((size_t)N_NODES * 4);
  size_t off_dinv   = alloc((size_t)N_NODES * 4);
  size_t off_rs     = alloc((size_t)(N_NODES + 1) * 4);
  size_t off_fill   = alloc((size_t)N_NODES * 4);
  size_t off_csrs   = alloc((size_t)(N_EDGES + N_NODES) * 4);
  size_t off_csrw   = alloc((size_t)(N_EDGES + N_NODES) * 4);
  size_t off_params = alloc((size_t)PARAMS_TOTAL * 4);
  size_t off_x      = alloc((size_t)N_NODES * HIDDEN * 4);
  size_t off_h      = alloc((size_t)N_NODES * HIDDEN * 4);
  size_t off_pool   = alloc((size_t)NGRAPHS * 256 * 4);
  size_t off_cnt    = alloc((size_t)NGRAPHS * 4);
  if (o > ws_size) return;   // workspace too small -- cannot proceed safely

  char* ws = (char*)d_ws;
  int*   flag     = (int*)(ws + off_flag);
  int*   deg      = (int*)(ws + off_deg);
  float* dinv     = (float*)(ws + off_dinv);
  int*   row_start= (int*)(ws + off_rs);
  int*   fill     = (int*)(ws + off_fill);
  int*   csr_src  = (int*)(ws + off_csrs);
  float* csr_w    = (float*)(ws + off_csrw);
  float* params   = (float*)(ws + off_params);
  float* x        = (float*)(ws + off_x);
  float* h        = (float*)(ws + off_h);
  float* pooled   = (float*)(ws + off_pool);
  float* counts   = (float*)(ws + off_cnt);

  const int* edge_src = (const int*)d_in[1];               // edge_index[0]
  const int* edge_dst = (const int*)d_in[1] + N_EDGES;     // edge_index[1]
  const int* batch    = (const int*)d_in[2];

  // ---- dtype detect + param dequant ----
  k_detect<<<1, 256, 0, stream>>>((const unsigned short*)d_in[3], flag);

  CvtArgs ca;
  const int srcIdx[15] = {0,3,4,5,6,7,8,9,10,11,12,13,14,15,16};
  const int ns[15]     = {150000,768,256,256,256,196608,768,768,768,65536,256,256,256,32768,128};
  const int offs[15]   = {OFF_POS,OFF_WIN,OFF_BIN,OFF_GIN,OFF_BEIN,OFF_CONVW,OFF_CONVB,OFF_GNG,OFF_GNB,
                          OFF_WO1,OFF_BO1,OFF_GO,OFF_BEO,OFF_WO2,OFF_BO2};
  for (int i = 0; i < 15; ++i){ ca.src[i] = d_in[srcIdx[i]]; ca.n[i] = ns[i]; ca.off[i] = offs[i]; }
  k_convert<<<512, 256, 0, stream>>>(ca, params, flag);

  // ---- graph preprocessing ----
  k_init<<<(N_NODES + 255) / 256, 256, 0, stream>>>(deg, fill, pooled, counts);
  k_deg<<<(N_EDGES + 255) / 256, 256, 0, stream>>>(edge_dst, deg);
  k_dinv<<<(N_NODES + 255) / 256, 256, 0, stream>>>(deg, dinv);
  k_scan<<<1, 256, 0, stream>>>(deg, row_start);
  k_fill<<<(N_EDGES + N_NODES + 255) / 256, 256, 0, stream>>>(edge_src, edge_dst, row_start, fill,
                                                              dinv, csr_src, csr_w);
  // ---- input projection ----
  k_input_proj<<<N_NODES / 4, 256, 0, stream>>>(params, x);

  // ---- GCN layers ----
  dim3 ggrid(256 / BN, (N_NODES + BM - 1) / BM);
  for (int l = 0; l < NLAYERS; ++l){
    k_gemm<<<ggrid, 256, 0, stream>>>(x, params + OFF_CONVW + l * 65536, h, N_NODES);
    k_agg_norm<<<N_NODES / 4, 256, 0, stream>>>(h, x, row_start, csr_src, csr_w, params, l);
  }

  // ---- pool + head ----
  k_pool<<<(N_NODES + 255) / 256, 256, 0, stream>>>(x, batch, pooled, counts);
  k_head<<<NGRAPHS, 256, 0, stream>>>(pooled, counts, params, d_out, flag);
}

// Round 3
// 538.930 us; speedup vs baseline: 1.4636x; 1.4636x over previous
//
#include <hip/hip_runtime.h>
#include <hip/hip_bf16.h>

#define N_NODES 50000
#define N_EDGES 300000
#define HIDDEN 256
#define ZDIM 128
#define NLAYERS 3
#define NGRAPHS 16
#define EPS 1e-5f

// ---- fp32 param region offsets (floats) ----
#define OFF_POS    0
#define OFF_WIN    150000
#define OFF_BIN    150768
#define OFF_GIN    151024
#define OFF_BEIN   151280
#define OFF_CONVW  151536
#define OFF_CONVB  348144
#define OFF_GNG    348912
#define OFF_GNB    349680
#define OFF_WO1    350448
#define OFF_BO1    415984
#define OFF_GO     416240
#define OFF_BEO    416496
#define OFF_WO2    416752
#define OFF_BO2    449520
#define PARAMS_TOTAL 449648

typedef __attribute__((ext_vector_type(8))) short short8;
typedef __attribute__((ext_vector_type(4))) float floatx4;

__device__ inline float wave_reduce_sum(float v){
#pragma unroll
  for (int off = 32; off; off >>= 1) v += __shfl_xor(v, off);
  return v;
}

__device__ inline ushort f2bf(float f){
  __hip_bfloat16 t = __float2bfloat16(f);
  return *(ushort*)&t;
}

// ---- dtype detection: flag=1 -> inputs stored fp32, flag=0 -> bf16 ----
__global__ void k_detect(const unsigned short* __restrict__ w_in, int* __restrict__ flag){
  __shared__ int sf;
  int tid = threadIdx.x;
  if (tid == 0) sf = 0;
  __syncthreads();
  for (int i = tid; i < 768; i += 256){
    int e = (w_in[i] >> 7) & 0xff;          // bf16 exponent field
    if (e >= 148) atomicOr(&sf, 1);         // |v| >= 2^20: impossible for real bf16 weights
  }
  __syncthreads();
  if (tid == 0) *flag = sf;
}

struct CvtArgs { const void* src[15]; int n[15]; int off[15]; };

__global__ void k_convert(CvtArgs a, float* __restrict__ params, const int* __restrict__ flag){
  const bool isf32 = (*flag != 0);
  int stride = gridDim.x * blockDim.x;
  int t0 = blockIdx.x * blockDim.x + threadIdx.x;
  for (int s = 0; s < 15; ++s){
    const void* src = a.src[s];
    int n = a.n[s];
    float* dst = params + a.off[s];
    if (isf32){
      const float* f = (const float*)src;
      for (int i = t0; i < n; i += stride) dst[i] = f[i];
    } else {
      const unsigned short* u = (const unsigned short*)src;
      for (int i = t0; i < n; i += stride){
        unsigned int w = ((unsigned int)u[i]) << 16;
        dst[i] = __uint_as_float(w);
      }
    }
  }
}

// Wt[l][n][k] = conv_W[l][k][n] as bf16 (transposed for MFMA B-fragment staging)
__global__ void k_wt(const float* __restrict__ params, ushort* __restrict__ Wt){
  int l = blockIdx.y;
  int n = blockIdx.x;
  int k = threadIdx.x;
  float v = params[OFF_CONVW + l * 65536 + k * 256 + n];
  Wt[l * 65536 + n * 256 + k] = f2bf(v);
}

__global__ void k_init(int* __restrict__ deg, int* __restrict__ fill,
                       float* __restrict__ pooled, float* __restrict__ counts){
  int i = blockIdx.x * blockDim.x + threadIdx.x;
  if (i < N_NODES){ deg[i] = 1; fill[i] = 0; }       // self-loop contributes 1
  if (i < NGRAPHS * 256) pooled[i] = 0.f;
  if (i < NGRAPHS) counts[i] = 0.f;
}

__global__ void k_deg(const int* __restrict__ dst, int* __restrict__ deg){
  int e = blockIdx.x * blockDim.x + threadIdx.x;
  if (e < N_EDGES) atomicAdd(&deg[dst[e]], 1);
}

__global__ void k_dinv(const int* __restrict__ deg, float* __restrict__ dinv){
  int i = blockIdx.x * blockDim.x + threadIdx.x;
  if (i < N_NODES) dinv[i] = rsqrtf((float)deg[i]);
}

// exclusive scan of deg -> row_start, single block of 256, 196 elems/thread serial
#define SCHUNK 196
__global__ __launch_bounds__(256) void k_scan(const int* __restrict__ deg, int* __restrict__ row_start){
  __shared__ int ssum[256];
  int tid = threadIdx.x;
  int beg = tid * SCHUNK;
  int end = min(beg + SCHUNK, N_NODES);
  int s = 0;
  for (int i = beg; i < end; ++i) s += deg[i];
  ssum[tid] = s;
  __syncthreads();
#pragma unroll
  for (int off = 1; off < 256; off <<= 1){
    int v = 0;
    if (tid >= off) v = ssum[tid - off];
    __syncthreads();
    ssum[tid] += v;
    __syncthreads();
  }
  int incl = ssum[tid];
  int run = incl - s;                       // exclusive offset
  for (int i = beg; i < end; ++i){ row_start[i] = run; run += deg[i]; }
  if (tid == 255) row_start[N_NODES] = incl;
}

__global__ void k_fill(const int* __restrict__ src, const int* __restrict__ dst,
                       const int* __restrict__ row_start, int* __restrict__ fill,
                       const float* __restrict__ dinv,
                       int* __restrict__ csr_src, float* __restrict__ csr_w){
  int t = blockIdx.x * blockDim.x + threadIdx.x;
  if (t >= N_EDGES + N_NODES) return;
  int s, d;
  if (t < N_EDGES){ s = src[t]; d = dst[t]; }
  else            { s = t - N_EDGES; d = s; }      // self loops
  int pos = row_start[d] + atomicAdd(&fill[d], 1);
  csr_src[pos] = s;
  csr_w[pos] = dinv[s] * dinv[d];
}

// input projection: Linear(3,256) -> ReLU -> GroupNorm(1,256). one wave per node.
// writes x (fp32, for residual) and x_bf (bf16 GEMM operand).
__global__ __launch_bounds__(256) void k_input_proj(const float* __restrict__ params,
                                                    float* __restrict__ x, ushort* __restrict__ x_bf){
  int lane = threadIdx.x & 63;
  int node = (blockIdx.x << 2) + (threadIdx.x >> 6);
  if (node >= N_NODES) return;
  const float* pos = params + OFF_POS + node * 3;
  float px = pos[0], py = pos[1], pz = pos[2];
  int c = lane * 4;
  const float* w0 = params + OFF_WIN;
  float v[4];
#pragma unroll
  for (int j = 0; j < 4; ++j){
    float t = params[OFF_BIN + c + j];
    t = fmaf(px, w0[c + j], t);
    t = fmaf(py, w0[256 + c + j], t);
    t = fmaf(pz, w0[512 + c + j], t);
    v[j] = fmaxf(t, 0.f);
  }
  float s  = v[0] + v[1] + v[2] + v[3];
  float ss = v[0]*v[0] + v[1]*v[1] + v[2]*v[2] + v[3]*v[3];
  s = wave_reduce_sum(s); ss = wave_reduce_sum(ss);
  float mean = s * (1.f/256.f);
  float var  = ss * (1.f/256.f) - mean * mean;
  float inv  = rsqrtf(var + EPS);
  float4 o;
  o.x = (v[0]-mean)*inv*params[OFF_GIN+c+0] + params[OFF_BEIN+c+0];
  o.y = (v[1]-mean)*inv*params[OFF_GIN+c+1] + params[OFF_BEIN+c+1];
  o.z = (v[2]-mean)*inv*params[OFF_GIN+c+2] + params[OFF_BEIN+c+2];
  o.w = (v[3]-mean)*inv*params[OFF_GIN+c+3] + params[OFF_BEIN+c+3];
  *(float4*)(x + node * 256 + c) = o;
  ushort4 ob = { f2bf(o.x), f2bf(o.y), f2bf(o.z), f2bf(o.w) };
  *(ushort4*)(x_bf + node * 256 + c) = ob;
}

// bf16 MFMA GEMM: Cb(Mx256 bf16) = A(Mx256 bf16) @ Wt^T.  Wt is [n][k].
// 128x128 tile, BK=64, 4 waves, each wave 64x64 via 4x4 mfma_f32_16x16x32_bf16.
#define GBM 128
#define LDK 72   // padded K-row length in shorts (bank stride 36 -> 2-way alias = free)
__global__ __launch_bounds__(256) void k_gemm_bf(const ushort* __restrict__ A, const ushort* __restrict__ Bt,
                                                 ushort* __restrict__ Cb, int M){
  __shared__ __align__(16) ushort As[GBM][LDK];
  __shared__ __align__(16) ushort Bs[GBM][LDK];
  int tid = threadIdx.x;
  int wave = tid >> 6, lane = tid & 63;
  int wr = wave >> 1, wc = wave & 1;
  int row0 = blockIdx.y * GBM;
  int col0 = blockIdx.x * GBM;
  int q = lane >> 4, l15 = lane & 15;
  floatx4 acc[4][4] = {};
  for (int k0 = 0; k0 < 256; k0 += 64){
    __syncthreads();
    // stage full 128-row x 64-short K-chunk for As and Bs:
    // 1024 (row,seg) slots per array, seg in 0..7 covers all 64 shorts.
#pragma unroll
    for (int i = 0; i < 4; ++i){
      int idx = tid + i * 256;
      int r = idx >> 3, seg = idx & 7;
      int gr = row0 + r;
      uint4 av = {0,0,0,0};
      if (gr < M) av = *(const uint4*)(A + gr * 256 + k0 + seg * 8);
      *(uint4*)&As[r][seg * 8] = av;
      uint4 bv = *(const uint4*)(Bt + (col0 + r) * 256 + k0 + seg * 8);
      *(uint4*)&Bs[r][seg * 8] = bv;
    }
    __syncthreads();
#pragma unroll
    for (int kk = 0; kk < 64; kk += 32){
      short8 af[4], bfr[4];
#pragma unroll
      for (int i = 0; i < 4; ++i)
        af[i] = *(const short8*)&As[wr * 64 + i * 16 + l15][kk + q * 8];
#pragma unroll
      for (int j = 0; j < 4; ++j)
        bfr[j] = *(const short8*)&Bs[wc * 64 + j * 16 + l15][kk + q * 8];
#pragma unroll
      for (int i = 0; i < 4; ++i)
#pragma unroll
        for (int j = 0; j < 4; ++j)
          acc[i][j] = __builtin_amdgcn_mfma_f32_16x16x32_bf16(af[i], bfr[j], acc[i][j], 0, 0, 0);
    }
  }
#pragma unroll
  for (int i = 0; i < 4; ++i){
#pragma unroll
    for (int r = 0; r < 4; ++r){
      int row = row0 + wr * 64 + i * 16 + q * 4 + r;
      if (row < M){
#pragma unroll
        for (int j = 0; j < 4; ++j){
          int col = col0 + wc * 64 + j * 16 + l15;
          Cb[row * 256 + col] = f2bf(acc[i][j][r]);
        }
      }
    }
  }
}

// aggregate over CSR (bf16 h) + bias + GroupNorm + ReLU + residual.
// writes x fp32 (in-place) and x_bf for the next layer's GEMM. one wave per node.
__global__ __launch_bounds__(256) void k_agg_norm(const ushort* __restrict__ hb, float* __restrict__ x,
    ushort* __restrict__ x_bf,
    const int* __restrict__ row_start, const int* __restrict__ csr_src, const float* __restrict__ csr_w,
    const float* __restrict__ params, int layer){
  int lane = threadIdx.x & 63;
  int node = (blockIdx.x << 2) + (threadIdx.x >> 6);
  if (node >= N_NODES) return;
  int c = lane * 4;
  float a0 = 0.f, a1 = 0.f, a2 = 0.f, a3 = 0.f;
  int p0 = row_start[node], p1 = row_start[node + 1];
  int p = p0;
  for (; p + 1 < p1; p += 2){
    int s0 = csr_src[p], s1 = csr_src[p + 1];
    float w0 = csr_w[p], w1 = csr_w[p + 1];
    uint2 v0 = *(const uint2*)(hb + s0 * 256 + c);
    uint2 v1 = *(const uint2*)(hb + s1 * 256 + c);
    a0 = fmaf(w0, __uint_as_float(v0.x << 16), a0);
    a1 = fmaf(w0, __uint_as_float(v0.x & 0xffff0000u), a1);
    a2 = fmaf(w0, __uint_as_float(v0.y << 16), a2);
    a3 = fmaf(w0, __uint_as_float(v0.y & 0xffff0000u), a3);
    a0 = fmaf(w1, __uint_as_float(v1.x << 16), a0);
    a1 = fmaf(w1, __uint_as_float(v1.x & 0xffff0000u), a1);
    a2 = fmaf(w1, __uint_as_float(v1.y << 16), a2);
    a3 = fmaf(w1, __uint_as_float(v1.y & 0xffff0000u), a3);
  }
  if (p < p1){
    int s0 = csr_src[p];
    float w0 = csr_w[p];
    uint2 v0 = *(const uint2*)(hb + s0 * 256 + c);
    a0 = fmaf(w0, __uint_as_float(v0.x << 16), a0);
    a1 = fmaf(w0, __uint_as_float(v0.x & 0xffff0000u), a1);
    a2 = fmaf(w0, __uint_as_float(v0.y << 16), a2);
    a3 = fmaf(w0, __uint_as_float(v0.y & 0xffff0000u), a3);
  }
  const float* cb = params + OFF_CONVB + layer * 256;
  float v[4] = { a0 + cb[c], a1 + cb[c+1], a2 + cb[c+2], a3 + cb[c+3] };
  float s  = v[0] + v[1] + v[2] + v[3];
  float ss = v[0]*v[0] + v[1]*v[1] + v[2]*v[2] + v[3]*v[3];
  s = wave_reduce_sum(s); ss = wave_reduce_sum(ss);
  float mean = s * (1.f/256.f);
  float var  = ss * (1.f/256.f) - mean * mean;
  float inv  = rsqrtf(var + EPS);
  const float* g = params + OFF_GNG + layer * 256;
  const float* b = params + OFF_GNB + layer * 256;
  float4 xo = *(float4*)(x + node * 256 + c);
  float4 o;
  o.x = fmaxf((v[0]-mean)*inv*g[c+0] + b[c+0], 0.f) + xo.x;
  o.y = fmaxf((v[1]-mean)*inv*g[c+1] + b[c+1], 0.f) + xo.y;
  o.z = fmaxf((v[2]-mean)*inv*g[c+2] + b[c+2], 0.f) + xo.z;
  o.w = fmaxf((v[3]-mean)*inv*g[c+3] + b[c+3], 0.f) + xo.w;
  *(float4*)(x + node * 256 + c) = o;
  ushort4 ob = { f2bf(o.x), f2bf(o.y), f2bf(o.z), f2bf(o.w) };
  *(ushort4*)(x_bf + node * 256 + c) = ob;
}

__global__ __launch_bounds__(256) void k_pool(const float* __restrict__ x, const int* __restrict__ batch,
                                              float* __restrict__ pooled, float* __restrict__ counts){
  __shared__ float lacc[NGRAPHS * 256];
  __shared__ int lcnt[NGRAPHS];
  int tid = threadIdx.x;
#pragma unroll
  for (int g = 0; g < NGRAPHS; ++g) lacc[g * 256 + tid] = 0.f;
  if (tid < NGRAPHS) lcnt[tid] = 0;
  __syncthreads();
  int base = blockIdx.x * 256;
  for (int j = 0; j < 256; ++j){
    int i = base + j;
    if (i >= N_NODES) break;                 // uniform across block
    int g = batch[i];
    lacc[g * 256 + tid] += x[i * 256 + tid];
    if (tid == 0) lcnt[g]++;
  }
  __syncthreads();
#pragma unroll
  for (int g = 0; g < NGRAPHS; ++g) atomicAdd(&pooled[g * 256 + tid], lacc[g * 256 + tid]);
  if (tid < NGRAPHS && lcnt[tid]) atomicAdd(&counts[tid], (float)lcnt[tid]);
}

__global__ __launch_bounds__(256) void k_head(const float* __restrict__ pooled, const float* __restrict__ counts,
    const float* __restrict__ params, void* __restrict__ out, const int* __restrict__ flag){
  __shared__ float m[256];
  __shared__ float hh[256];
  __shared__ float red[2][4];
  int g = blockIdx.x, tid = threadIdx.x;
  float cnt = fmaxf(counts[g], 1.f);
  m[tid] = pooled[g * 256 + tid] / cnt;
  __syncthreads();
  const float* W1 = params + OFF_WO1;
  float acc = params[OFF_BO1 + tid];
  for (int k = 0; k < 256; ++k) acc = fmaf(m[k], W1[k * 256 + tid], acc);
  acc = fmaxf(acc, 0.f);
  float s = wave_reduce_sum(acc), ss = wave_reduce_sum(acc * acc);
  int wv = tid >> 6, lane = tid & 63;
  if (lane == 0){ red[0][wv] = s; red[1][wv] = ss; }
  __syncthreads();
  float S  = red[0][0] + red[0][1] + red[0][2] + red[0][3];
  float SS = red[1][0] + red[1][1] + red[1][2] + red[1][3];
  float mean = S * (1.f/256.f);
  float var  = SS * (1.f/256.f) - mean * mean;
  float inv  = rsqrtf(var + EPS);
  float hn = (acc - mean) * inv * params[OFF_GO + tid] + params[OFF_BEO + tid];
  hh[tid] = hn;
  __syncthreads();
  if (tid < ZDIM){
    const float* W2 = params + OFF_WO2;
    float o = params[OFF_BO2 + tid];
    for (int k = 0; k < 256; ++k) o = fmaf(hh[k], W2[k * 128 + tid], o);
    if (*flag) ((float*)out)[g * 128 + tid] = o;
    else       ((__hip_bfloat16*)out)[g * 128 + tid] = __float2bfloat16(o);
  }
}

extern "C" void kernel_launch(void* const* d_in, const int* in_sizes, int n_in,
                              void* d_out, int out_size, void* d_ws, size_t ws_size,
                              hipStream_t stream){
  // ---- workspace layout ----
  size_t o = 0;
  auto alloc = [&](size_t bytes)->size_t{ size_t r = o; o = (o + bytes + 255) & ~(size_t)255; return r; };
  size_t off_flag   = alloc(4);
  size_t off_deg    = alloc((size_t)N_NODES * 4);
  size_t off_dinv   = alloc((size_t)N_NODES * 4);
  size_t off_rs     = alloc((size_t)(N_NODES + 1) * 4);
  size_t off_fill   = alloc((size_t)N_NODES * 4);
  size_t off_csrs   = alloc((size_t)(N_EDGES + N_NODES) * 4);
  size_t off_csrw   = alloc((size_t)(N_EDGES + N_NODES) * 4);
  size_t off_params = alloc((size_t)PARAMS_TOTAL * 4);
  size_t off_x      = alloc((size_t)N_NODES * HIDDEN * 4);
  size_t off_xbf    = alloc((size_t)N_NODES * HIDDEN * 2);
  size_t off_hbf    = alloc((size_t)N_NODES * HIDDEN * 2);
  size_t off_wt     = alloc((size_t)NLAYERS * HIDDEN * HIDDEN * 2);
  size_t off_pool   = alloc((size_t)NGRAPHS * 256 * 4);
  size_t off_cnt    = alloc((size_t)NGRAPHS * 4);
  if (o > ws_size) return;   // workspace too small -- cannot proceed safely

  char* ws = (char*)d_ws;
  int*    flag     = (int*)(ws + off_flag);
  int*    deg      = (int*)(ws + off_deg);
  float*  dinv     = (float*)(ws + off_dinv);
  int*    row_start= (int*)(ws + off_rs);
  int*    fill     = (int*)(ws + off_fill);
  int*    csr_src  = (int*)(ws + off_csrs);
  float*  csr_w    = (float*)(ws + off_csrw);
  float*  params   = (float*)(ws + off_params);
  float*  x        = (float*)(ws + off_x);
  ushort* x_bf     = (ushort*)(ws + off_xbf);
  ushort* h_bf     = (ushort*)(ws + off_hbf);
  ushort* Wt       = (ushort*)(ws + off_wt);
  float*  pooled   = (float*)(ws + off_pool);
  float*  counts   = (float*)(ws + off_cnt);

  const int* edge_src = (const int*)d_in[1];               // edge_index[0]
  const int* edge_dst = (const int*)d_in[1] + N_EDGES;     // edge_index[1]
  const int* batch    = (const int*)d_in[2];

  // ---- dtype detect + param dequant ----
  k_detect<<<1, 256, 0, stream>>>((const unsigned short*)d_in[3], flag);

  CvtArgs ca;
  const int srcIdx[15] = {0,3,4,5,6,7,8,9,10,11,12,13,14,15,16};
  const int ns[15]     = {150000,768,256,256,256,196608,768,768,768,65536,256,256,256,32768,128};
  const int offs[15]   = {OFF_POS,OFF_WIN,OFF_BIN,OFF_GIN,OFF_BEIN,OFF_CONVW,OFF_CONVB,OFF_GNG,OFF_GNB,
                          OFF_WO1,OFF_BO1,OFF_GO,OFF_BEO,OFF_WO2,OFF_BO2};
  for (int i = 0; i < 15; ++i){ ca.src[i] = d_in[srcIdx[i]]; ca.n[i] = ns[i]; ca.off[i] = offs[i]; }
  k_convert<<<512, 256, 0, stream>>>(ca, params, flag);
  k_wt<<<dim3(256, NLAYERS), 256, 0, stream>>>(params, Wt);

  // ---- graph preprocessing ----
  k_init<<<(N_NODES + 255) / 256, 256, 0, stream>>>(deg, fill, pooled, counts);
  k_deg<<<(N_EDGES + 255) / 256, 256, 0, stream>>>(edge_dst, deg);
  k_dinv<<<(N_NODES + 255) / 256, 256, 0, stream>>>(deg, dinv);
  k_scan<<<1, 256, 0, stream>>>(deg, row_start);
  k_fill<<<(N_EDGES + N_NODES + 255) / 256, 256, 0, stream>>>(edge_src, edge_dst, row_start, fill,
                                                              dinv, csr_src, csr_w);
  // ---- input projection ----
  k_input_proj<<<N_NODES / 4, 256, 0, stream>>>(params, x, x_bf);

  // ---- GCN layers (bf16 MFMA GEMM + fused aggregate/norm) ----
  dim3 ggrid(2, (N_NODES + GBM - 1) / GBM);
  for (int l = 0; l < NLAYERS; ++l){
    k_gemm_bf<<<ggrid, 256, 0, stream>>>(x_bf, Wt + l * 65536, h_bf, N_NODES);
    k_agg_norm<<<N_NODES / 4, 256, 0, stream>>>(h_bf, x, x_bf, row_start, csr_src, csr_w, params, l);
  }

  // ---- pool + head ----
  k_pool<<<(N_NODES + 255) / 256, 256, 0, stream>>>(x, batch, pooled, counts);
  k_head<<<NGRAPHS, 256, 0, stream>>>(pooled, counts, params, d_out, flag);
}

// Round 4
// 433.394 us; speedup vs baseline: 1.8201x; 1.2435x over previous
//
#include <hip/hip_runtime.h>
#include <hip/hip_bf16.h>

#define N_NODES 50000
#define N_EDGES 300000
#define HIDDEN 256
#define ZDIM 128
#define NLAYERS 3
#define NGRAPHS 16
#define EPS 1e-5f
#define NSCANBLK 196   // ceil(50000/256)

// ---- fp32 param region offsets (floats) ----
#define OFF_POS    0
#define OFF_WIN    150000
#define OFF_BIN    150768
#define OFF_GIN    151024
#define OFF_BEIN   151280
#define OFF_CONVW  151536
#define OFF_CONVB  348144
#define OFF_GNG    348912
#define OFF_GNB    349680
#define OFF_WO1    350448
#define OFF_BO1    415984
#define OFF_GO     416240
#define OFF_BEO    416496
#define OFF_WO2    416752
#define OFF_BO2    449520
#define PARAMS_TOTAL 449648

typedef __attribute__((ext_vector_type(8))) short short8;
typedef __attribute__((ext_vector_type(4))) float floatx4;

__device__ inline float wave_reduce_sum(float v){
#pragma unroll
  for (int off = 32; off; off >>= 1) v += __shfl_xor(v, off);
  return v;
}

__device__ inline ushort f2bf(float f){
  __hip_bfloat16 t = __float2bfloat16(f);
  return *(ushort*)&t;
}

// ---- dtype detection: flag=1 -> inputs stored fp32, flag=0 -> bf16 ----
__global__ void k_detect(const unsigned short* __restrict__ w_in, int* __restrict__ flag){
  __shared__ int sf;
  int tid = threadIdx.x;
  if (tid == 0) sf = 0;
  __syncthreads();
  for (int i = tid; i < 768; i += 256){
    int e = (w_in[i] >> 7) & 0xff;          // bf16 exponent field
    if (e >= 148) atomicOr(&sf, 1);         // |v| >= 2^20: impossible for real bf16 weights
  }
  __syncthreads();
  if (tid == 0) *flag = sf;
}

struct CvtArgs { const void* src[15]; int n[15]; int off[15]; };

__global__ void k_convert(CvtArgs a, float* __restrict__ params, const int* __restrict__ flag){
  const bool isf32 = (*flag != 0);
  int stride = gridDim.x * blockDim.x;
  int t0 = blockIdx.x * blockDim.x + threadIdx.x;
  for (int s = 0; s < 15; ++s){
    const void* src = a.src[s];
    int n = a.n[s];
    float* dst = params + a.off[s];
    if (isf32){
      const float* f = (const float*)src;
      for (int i = t0; i < n; i += stride) dst[i] = f[i];
    } else {
      const unsigned short* u = (const unsigned short*)src;
      for (int i = t0; i < n; i += stride){
        unsigned int w = ((unsigned int)u[i]) << 16;
        dst[i] = __uint_as_float(w);
      }
    }
  }
}

// Wt[l][n][k] = conv_W[l][k][n] as bf16 (transposed for MFMA B-fragment staging)
__global__ void k_wt(const float* __restrict__ params, ushort* __restrict__ Wt){
  int l = blockIdx.y;
  int n = blockIdx.x;
  int k = threadIdx.x;
  float v = params[OFF_CONVW + l * 65536 + k * 256 + n];
  Wt[l * 65536 + n * 256 + k] = f2bf(v);
}

__global__ void k_init(int* __restrict__ deg, int* __restrict__ fill,
                       float* __restrict__ pooled, float* __restrict__ counts){
  int i = blockIdx.x * blockDim.x + threadIdx.x;
  if (i < N_NODES){ deg[i] = 1; fill[i] = 0; }       // self-loop contributes 1
  if (i < NGRAPHS * 256) pooled[i] = 0.f;
  if (i < NGRAPHS) counts[i] = 0.f;
}

__global__ void k_deg(const int* __restrict__ dst, int* __restrict__ deg){
  int e = blockIdx.x * blockDim.x + threadIdx.x;
  if (e < N_EDGES) atomicAdd(&deg[dst[e]], 1);
}

__global__ void k_dinv(const int* __restrict__ deg, float* __restrict__ dinv){
  int i = blockIdx.x * blockDim.x + threadIdx.x;
  if (i < N_NODES) dinv[i] = rsqrtf((float)deg[i]);
}

// ---- hierarchical exclusive scan of deg -> row_start ----
// pass 1: per-block (256-wide) inclusive scan; row_start[i] = inclusive-within-block; bsum[b] = block total
__global__ __launch_bounds__(256) void k_scan1(const int* __restrict__ deg, int* __restrict__ row_start,
                                               int* __restrict__ bsum){
  __shared__ int sd[256];
  int tid = threadIdx.x;
  int i = blockIdx.x * 256 + tid;
  int v = (i < N_NODES) ? deg[i] : 0;
  sd[tid] = v;
  __syncthreads();
#pragma unroll
  for (int off = 1; off < 256; off <<= 1){
    int t = (tid >= off) ? sd[tid - off] : 0;
    __syncthreads();
    sd[tid] += t;
    __syncthreads();
  }
  if (i < N_NODES) row_start[i] = sd[tid];
  if (tid == 255) bsum[blockIdx.x] = sd[255];
}

// pass 2: single block, exclusive scan of the NSCANBLK block sums -> boff; total -> row_start[N_NODES]
__global__ __launch_bounds__(256) void k_scan2(const int* __restrict__ bsum, int* __restrict__ boff,
                                               int* __restrict__ row_start){
  __shared__ int sd[256];
  int tid = threadIdx.x;
  int v = (tid < NSCANBLK) ? bsum[tid] : 0;
  sd[tid] = v;
  __syncthreads();
#pragma unroll
  for (int off = 1; off < 256; off <<= 1){
    int t = (tid >= off) ? sd[tid - off] : 0;
    __syncthreads();
    sd[tid] += t;
    __syncthreads();
  }
  if (tid < NSCANBLK) boff[tid] = sd[tid] - v;   // exclusive
  if (tid == NSCANBLK - 1) row_start[N_NODES] = sd[tid];
}

// pass 3: globalize + convert to exclusive: row_start[i] += boff[b] - deg[i]
__global__ __launch_bounds__(256) void k_scan3(const int* __restrict__ deg, const int* __restrict__ boff,
                                               int* __restrict__ row_start){
  int i = blockIdx.x * 256 + threadIdx.x;
  if (i < N_NODES) row_start[i] = row_start[i] + boff[blockIdx.x] - deg[i];
}

__global__ void k_fill(const int* __restrict__ src, const int* __restrict__ dst,
                       const int* __restrict__ row_start, int* __restrict__ fill,
                       const float* __restrict__ dinv,
                       int* __restrict__ csr_src, float* __restrict__ csr_w){
  int t = blockIdx.x * blockDim.x + threadIdx.x;
  if (t >= N_EDGES + N_NODES) return;
  int s, d;
  if (t < N_EDGES){ s = src[t]; d = dst[t]; }
  else            { s = t - N_EDGES; d = s; }      // self loops
  int pos = row_start[d] + atomicAdd(&fill[d], 1);
  csr_src[pos] = s;
  csr_w[pos] = dinv[s] * dinv[d];
}

// input projection: Linear(3,256) -> ReLU -> GroupNorm(1,256). one wave per node.
// writes x (fp32, for residual) and x_bf (bf16 GEMM operand).
__global__ __launch_bounds__(256) void k_input_proj(const float* __restrict__ params,
                                                    float* __restrict__ x, ushort* __restrict__ x_bf){
  int lane = threadIdx.x & 63;
  int node = (blockIdx.x << 2) + (threadIdx.x >> 6);
  if (node >= N_NODES) return;
  const float* pos = params + OFF_POS + node * 3;
  float px = pos[0], py = pos[1], pz = pos[2];
  int c = lane * 4;
  const float* w0 = params + OFF_WIN;
  float v[4];
#pragma unroll
  for (int j = 0; j < 4; ++j){
    float t = params[OFF_BIN + c + j];
    t = fmaf(px, w0[c + j], t);
    t = fmaf(py, w0[256 + c + j], t);
    t = fmaf(pz, w0[512 + c + j], t);
    v[j] = fmaxf(t, 0.f);
  }
  float s  = v[0] + v[1] + v[2] + v[3];
  float ss = v[0]*v[0] + v[1]*v[1] + v[2]*v[2] + v[3]*v[3];
  s = wave_reduce_sum(s); ss = wave_reduce_sum(ss);
  float mean = s * (1.f/256.f);
  float var  = ss * (1.f/256.f) - mean * mean;
  float inv  = rsqrtf(var + EPS);
  float4 o;
  o.x = (v[0]-mean)*inv*params[OFF_GIN+c+0] + params[OFF_BEIN+c+0];
  o.y = (v[1]-mean)*inv*params[OFF_GIN+c+1] + params[OFF_BEIN+c+1];
  o.z = (v[2]-mean)*inv*params[OFF_GIN+c+2] + params[OFF_BEIN+c+2];
  o.w = (v[3]-mean)*inv*params[OFF_GIN+c+3] + params[OFF_BEIN+c+3];
  *(float4*)(x + node * 256 + c) = o;
  ushort4 ob = { f2bf(o.x), f2bf(o.y), f2bf(o.z), f2bf(o.w) };
  *(ushort4*)(x_bf + node * 256 + c) = ob;
}

// bf16 MFMA GEMM: Cb(Mx256 bf16) = A(Mx256 bf16) @ Wt^T.  Wt is [n][k].
// 128x128 tile, BK=64, 4 waves, each wave 64x64 via 4x4 mfma_f32_16x16x32_bf16.
#define GBM 128
#define LDK 72   // padded K-row length in shorts (bank stride 36 -> 2-way alias = free)
__global__ __launch_bounds__(256) void k_gemm_bf(const ushort* __restrict__ A, const ushort* __restrict__ Bt,
                                                 ushort* __restrict__ Cb, int M){
  __shared__ __align__(16) ushort As[GBM][LDK];
  __shared__ __align__(16) ushort Bs[GBM][LDK];
  int tid = threadIdx.x;
  int wave = tid >> 6, lane = tid & 63;
  int wr = wave >> 1, wc = wave & 1;
  int row0 = blockIdx.y * GBM;
  int col0 = blockIdx.x * GBM;
  int q = lane >> 4, l15 = lane & 15;
  floatx4 acc[4][4] = {};
  for (int k0 = 0; k0 < 256; k0 += 64){
    __syncthreads();
    // stage full 128-row x 64-short K-chunk for As and Bs (1024 row,seg slots each)
#pragma unroll
    for (int i = 0; i < 4; ++i){
      int idx = tid + i * 256;
      int r = idx >> 3, seg = idx & 7;
      int gr = row0 + r;
      uint4 av = {0,0,0,0};
      if (gr < M) av = *(const uint4*)(A + gr * 256 + k0 + seg * 8);
      *(uint4*)&As[r][seg * 8] = av;
      uint4 bv = *(const uint4*)(Bt + (col0 + r) * 256 + k0 + seg * 8);
      *(uint4*)&Bs[r][seg * 8] = bv;
    }
    __syncthreads();
#pragma unroll
    for (int kk = 0; kk < 64; kk += 32){
      short8 af[4], bfr[4];
#pragma unroll
      for (int i = 0; i < 4; ++i)
        af[i] = *(const short8*)&As[wr * 64 + i * 16 + l15][kk + q * 8];
#pragma unroll
      for (int j = 0; j < 4; ++j)
        bfr[j] = *(const short8*)&Bs[wc * 64 + j * 16 + l15][kk + q * 8];
#pragma unroll
      for (int i = 0; i < 4; ++i)
#pragma unroll
        for (int j = 0; j < 4; ++j)
          acc[i][j] = __builtin_amdgcn_mfma_f32_16x16x32_bf16(af[i], bfr[j], acc[i][j], 0, 0, 0);
    }
  }
#pragma unroll
  for (int i = 0; i < 4; ++i){
#pragma unroll
    for (int r = 0; r < 4; ++r){
      int row = row0 + wr * 64 + i * 16 + q * 4 + r;
      if (row < M){
#pragma unroll
        for (int j = 0; j < 4; ++j){
          int col = col0 + wc * 64 + j * 16 + l15;
          Cb[row * 256 + col] = f2bf(acc[i][j][r]);
        }
      }
    }
  }
}

// aggregate over CSR (bf16 h) + bias + GroupNorm + ReLU + residual.
// writes x fp32 (in-place) and x_bf for the next layer's GEMM. one wave per node.
__global__ __launch_bounds__(256) void k_agg_norm(const ushort* __restrict__ hb, float* __restrict__ x,
    ushort* __restrict__ x_bf,
    const int* __restrict__ row_start, const int* __restrict__ csr_src, const float* __restrict__ csr_w,
    const float* __restrict__ params, int layer){
  int lane = threadIdx.x & 63;
  int node = (blockIdx.x << 2) + (threadIdx.x >> 6);
  if (node >= N_NODES) return;
  int c = lane * 4;
  float a0 = 0.f, a1 = 0.f, a2 = 0.f, a3 = 0.f;
  int p0 = row_start[node], p1 = row_start[node + 1];
  int p = p0;
  for (; p + 1 < p1; p += 2){
    int s0 = csr_src[p], s1 = csr_src[p + 1];
    float w0 = csr_w[p], w1 = csr_w[p + 1];
    uint2 v0 = *(const uint2*)(hb + s0 * 256 + c);
    uint2 v1 = *(const uint2*)(hb + s1 * 256 + c);
    a0 = fmaf(w0, __uint_as_float(v0.x << 16), a0);
    a1 = fmaf(w0, __uint_as_float(v0.x & 0xffff0000u), a1);
    a2 = fmaf(w0, __uint_as_float(v0.y << 16), a2);
    a3 = fmaf(w0, __uint_as_float(v0.y & 0xffff0000u), a3);
    a0 = fmaf(w1, __uint_as_float(v1.x << 16), a0);
    a1 = fmaf(w1, __uint_as_float(v1.x & 0xffff0000u), a1);
    a2 = fmaf(w1, __uint_as_float(v1.y << 16), a2);
    a3 = fmaf(w1, __uint_as_float(v1.y & 0xffff0000u), a3);
  }
  if (p < p1){
    int s0 = csr_src[p];
    float w0 = csr_w[p];
    uint2 v0 = *(const uint2*)(hb + s0 * 256 + c);
    a0 = fmaf(w0, __uint_as_float(v0.x << 16), a0);
    a1 = fmaf(w0, __uint_as_float(v0.x & 0xffff0000u), a1);
    a2 = fmaf(w0, __uint_as_float(v0.y << 16), a2);
    a3 = fmaf(w0, __uint_as_float(v0.y & 0xffff0000u), a3);
  }
  const float* cb = params + OFF_CONVB + layer * 256;
  float v[4] = { a0 + cb[c], a1 + cb[c+1], a2 + cb[c+2], a3 + cb[c+3] };
  float s  = v[0] + v[1] + v[2] + v[3];
  float ss = v[0]*v[0] + v[1]*v[1] + v[2]*v[2] + v[3]*v[3];
  s = wave_reduce_sum(s); ss = wave_reduce_sum(ss);
  float mean = s * (1.f/256.f);
  float var  = ss * (1.f/256.f) - mean * mean;
  float inv  = rsqrtf(var + EPS);
  const float* g = params + OFF_GNG + layer * 256;
  const float* b = params + OFF_GNB + layer * 256;
  float4 xo = *(float4*)(x + node * 256 + c);
  float4 o;
  o.x = fmaxf((v[0]-mean)*inv*g[c+0] + b[c+0], 0.f) + xo.x;
  o.y = fmaxf((v[1]-mean)*inv*g[c+1] + b[c+1], 0.f) + xo.y;
  o.z = fmaxf((v[2]-mean)*inv*g[c+2] + b[c+2], 0.f) + xo.z;
  o.w = fmaxf((v[3]-mean)*inv*g[c+3] + b[c+3], 0.f) + xo.w;
  *(float4*)(x + node * 256 + c) = o;
  ushort4 ob = { f2bf(o.x), f2bf(o.y), f2bf(o.z), f2bf(o.w) };
  *(ushort4*)(x_bf + node * 256 + c) = ob;
}

// global mean pool: 782 blocks x 4 waves; wave owns 16 nodes, lane owns 4 channels.
// register accumulation, atomic flush only at sorted-batch segment boundaries.
#define PCH 16   // nodes per wave
__global__ __launch_bounds__(256) void k_pool(const float* __restrict__ x, const int* __restrict__ batch,
                                              float* __restrict__ pooled, float* __restrict__ counts){
  int tid = threadIdx.x;
  int wave = tid >> 6, lane = tid & 63;
  int c = lane * 4;
  int n0 = blockIdx.x * (4 * PCH) + wave * PCH;
  int n1 = min(n0 + PCH, N_NODES);
  if (n0 >= N_NODES) return;
  float4 acc = {0.f, 0.f, 0.f, 0.f};
  int cur = batch[n0];
  int cnt = 0;
  for (int i = n0; i < n1; ++i){
    int g = batch[i];
    if (g != cur){                       // wave-uniform branch
      float* p = pooled + cur * 256 + c;
      atomicAdd(p + 0, acc.x); atomicAdd(p + 1, acc.y);
      atomicAdd(p + 2, acc.z); atomicAdd(p + 3, acc.w);
      if (lane == 0) atomicAdd(&counts[cur], (float)cnt);
      acc = {0.f, 0.f, 0.f, 0.f}; cnt = 0; cur = g;
    }
    float4 v = *(const float4*)(x + (size_t)i * 256 + c);
    acc.x += v.x; acc.y += v.y; acc.z += v.z; acc.w += v.w;
    cnt++;
  }
  float* p = pooled + cur * 256 + c;
  atomicAdd(p + 0, acc.x); atomicAdd(p + 1, acc.y);
  atomicAdd(p + 2, acc.z); atomicAdd(p + 3, acc.w);
  if (lane == 0) atomicAdd(&counts[cur], (float)cnt);
}

__global__ __launch_bounds__(256) void k_head(const float* __restrict__ pooled, const float* __restrict__ counts,
    const float* __restrict__ params, void* __restrict__ out, const int* __restrict__ flag){
  __shared__ float m[256];
  __shared__ float hh[256];
  __shared__ float red[2][4];
  int g = blockIdx.x, tid = threadIdx.x;
  float cnt = fmaxf(counts[g], 1.f);
  m[tid] = pooled[g * 256 + tid] / cnt;
  __syncthreads();
  const float* W1 = params + OFF_WO1;
  float acc = params[OFF_BO1 + tid];
  for (int k = 0; k < 256; ++k) acc = fmaf(m[k], W1[k * 256 + tid], acc);
  acc = fmaxf(acc, 0.f);
  float s = wave_reduce_sum(acc), ss = wave_reduce_sum(acc * acc);
  int wv = tid >> 6, lane = tid & 63;
  if (lane == 0){ red[0][wv] = s; red[1][wv] = ss; }
  __syncthreads();
  float S  = red[0][0] + red[0][1] + red[0][2] + red[0][3];
  float SS = red[1][0] + red[1][1] + red[1][2] + red[1][3];
  float mean = S * (1.f/256.f);
  float var  = SS * (1.f/256.f) - mean * mean;
  float inv  = rsqrtf(var + EPS);
  float hn = (acc - mean) * inv * params[OFF_GO + tid] + params[OFF_BEO + tid];
  hh[tid] = hn;
  __syncthreads();
  if (tid < ZDIM){
    const float* W2 = params + OFF_WO2;
    float o = params[OFF_BO2 + tid];
    for (int k = 0; k < 256; ++k) o = fmaf(hh[k], W2[k * 128 + tid], o);
    if (*flag) ((float*)out)[g * 128 + tid] = o;
    else       ((__hip_bfloat16*)out)[g * 128 + tid] = __float2bfloat16(o);
  }
}

extern "C" void kernel_launch(void* const* d_in, const int* in_sizes, int n_in,
                              void* d_out, int out_size, void* d_ws, size_t ws_size,
                              hipStream_t stream){
  // ---- workspace layout ----
  size_t o = 0;
  auto alloc = [&](size_t bytes)->size_t{ size_t r = o; o = (o + bytes + 255) & ~(size_t)255; return r; };
  size_t off_flag   = alloc(4);
  size_t off_deg    = alloc((size_t)N_NODES * 4);
  size_t off_dinv   = alloc((size_t)N_NODES * 4);
  size_t off_rs     = alloc((size_t)(N_NODES + 1) * 4);
  size_t off_fill   = alloc((size_t)N_NODES * 4);
  size_t off_bsum   = alloc((size_t)NSCANBLK * 4);
  size_t off_boff   = alloc((size_t)NSCANBLK * 4);
  size_t off_csrs   = alloc((size_t)(N_EDGES + N_NODES) * 4);
  size_t off_csrw   = alloc((size_t)(N_EDGES + N_NODES) * 4);
  size_t off_params = alloc((size_t)PARAMS_TOTAL * 4);
  size_t off_x      = alloc((size_t)N_NODES * HIDDEN * 4);
  size_t off_xbf    = alloc((size_t)N_NODES * HIDDEN * 2);
  size_t off_hbf    = alloc((size_t)N_NODES * HIDDEN * 2);
  size_t off_wt     = alloc((size_t)NLAYERS * HIDDEN * HIDDEN * 2);
  size_t off_pool   = alloc((size_t)NGRAPHS * 256 * 4);
  size_t off_cnt    = alloc((size_t)NGRAPHS * 4);
  if (o > ws_size) return;   // workspace too small -- cannot proceed safely

  char* ws = (char*)d_ws;
  int*    flag     = (int*)(ws + off_flag);
  int*    deg      = (int*)(ws + off_deg);
  float*  dinv     = (float*)(ws + off_dinv);
  int*    row_start= (int*)(ws + off_rs);
  int*    fill     = (int*)(ws + off_fill);
  int*    bsum     = (int*)(ws + off_bsum);
  int*    boff     = (int*)(ws + off_boff);
  int*    csr_src  = (int*)(ws + off_csrs);
  float*  csr_w    = (float*)(ws + off_csrw);
  float*  params   = (float*)(ws + off_params);
  float*  x        = (float*)(ws + off_x);
  ushort* x_bf     = (ushort*)(ws + off_xbf);
  ushort* h_bf     = (ushort*)(ws + off_hbf);
  ushort* Wt       = (ushort*)(ws + off_wt);
  float*  pooled   = (float*)(ws + off_pool);
  float*  counts   = (float*)(ws + off_cnt);

  const int* edge_src = (const int*)d_in[1];               // edge_index[0]
  const int* edge_dst = (const int*)d_in[1] + N_EDGES;     // edge_index[1]
  const int* batch    = (const int*)d_in[2];

  // ---- dtype detect + param dequant ----
  k_detect<<<1, 256, 0, stream>>>((const unsigned short*)d_in[3], flag);

  CvtArgs ca;
  const int srcIdx[15] = {0,3,4,5,6,7,8,9,10,11,12,13,14,15,16};
  const int ns[15]     = {150000,768,256,256,256,196608,768,768,768,65536,256,256,256,32768,128};
  const int offs[15]   = {OFF_POS,OFF_WIN,OFF_BIN,OFF_GIN,OFF_BEIN,OFF_CONVW,OFF_CONVB,OFF_GNG,OFF_GNB,
                          OFF_WO1,OFF_BO1,OFF_GO,OFF_BEO,OFF_WO2,OFF_BO2};
  for (int i = 0; i < 15; ++i){ ca.src[i] = d_in[srcIdx[i]]; ca.n[i] = ns[i]; ca.off[i] = offs[i]; }
  k_convert<<<512, 256, 0, stream>>>(ca, params, flag);
  k_wt<<<dim3(256, NLAYERS), 256, 0, stream>>>(params, Wt);

  // ---- graph preprocessing ----
  k_init<<<(N_NODES + 255) / 256, 256, 0, stream>>>(deg, fill, pooled, counts);
  k_deg<<<(N_EDGES + 255) / 256, 256, 0, stream>>>(edge_dst, deg);
  k_dinv<<<(N_NODES + 255) / 256, 256, 0, stream>>>(deg, dinv);
  k_scan1<<<NSCANBLK, 256, 0, stream>>>(deg, row_start, bsum);
  k_scan2<<<1, 256, 0, stream>>>(bsum, boff, row_start);
  k_scan3<<<NSCANBLK, 256, 0, stream>>>(deg, boff, row_start);
  k_fill<<<(N_EDGES + N_NODES + 255) / 256, 256, 0, stream>>>(edge_src, edge_dst, row_start, fill,
                                                              dinv, csr_src, csr_w);
  // ---- input projection ----
  k_input_proj<<<N_NODES / 4, 256, 0, stream>>>(params, x, x_bf);

  // ---- GCN layers (bf16 MFMA GEMM + fused aggregate/norm) ----
  dim3 ggrid(2, (N_NODES + GBM - 1) / GBM);
  for (int l = 0; l < NLAYERS; ++l){
    k_gemm_bf<<<ggrid, 256, 0, stream>>>(x_bf, Wt + l * 65536, h_bf, N_NODES);
    k_agg_norm<<<N_NODES / 4, 256, 0, stream>>>(h_bf, x, x_bf, row_start, csr_src, csr_w, params, l);
  }

  // ---- pool + head ----
  k_pool<<<(N_NODES + 4 * PCH - 1) / (4 * PCH), 256, 0, stream>>>(x, batch, pooled, counts);
  k_head<<<NGRAPHS, 256, 0, stream>>>(pooled, counts, params, d_out, flag);
}

// Round 5
// 396.987 us; speedup vs baseline: 1.9870x; 1.0917x over previous
//
#include <hip/hip_runtime.h>
#include <hip/hip_bf16.h>

#define N_NODES 50000
#define N_EDGES 300000
#define HIDDEN 256
#define ZDIM 128
#define NLAYERS 3
#define NGRAPHS 16
#define EPS 1e-5f
#define NSCANBLK 196   // ceil(50000/256)

// ---- fp32 param region offsets (floats) ---- (conv_W region unused now; offsets kept stable)
#define OFF_POS    0
#define OFF_WIN    150000
#define OFF_BIN    150768
#define OFF_GIN    151024
#define OFF_BEIN   151280
#define OFF_CONVB  348144
#define OFF_GNG    348912
#define OFF_GNB    349680
#define OFF_WO1    350448
#define OFF_BO1    415984
#define OFF_GO     416240
#define OFF_BEO    416496
#define OFF_WO2    416752
#define OFF_BO2    449520
#define PARAMS_TOTAL 449648

typedef __attribute__((ext_vector_type(8))) short short8;
typedef __attribute__((ext_vector_type(4))) float floatx4;

__device__ inline float wave_reduce_sum(float v){
#pragma unroll
  for (int off = 32; off; off >>= 1) v += __shfl_xor(v, off);
  return v;
}

__device__ inline ushort f2bf(float f){
  __hip_bfloat16 t = __float2bfloat16(f);
  return *(ushort*)&t;
}
__device__ inline float bflo(unsigned int u){ return __uint_as_float(u << 16); }
__device__ inline float bfhi(unsigned int u){ return __uint_as_float(u & 0xffff0000u); }

struct PrepArgs { const void* src[14]; int n[14]; int off[14]; const void* win; const void* convw; };

// fused: per-block dtype detect + param convert (14 tensors) + Wt build (transposed bf16 conv_W)
__global__ __launch_bounds__(256) void k_prep(PrepArgs a, float* __restrict__ params,
                                              ushort* __restrict__ Wt, int* __restrict__ flag){
  __shared__ int sf;
  int tid = threadIdx.x;
  if (tid == 0) sf = 0;
  __syncthreads();
  const unsigned short* w = (const unsigned short*)a.win;
  for (int i = tid; i < 768; i += 256){
    int e = (w[i] >> 7) & 0xff;            // bf16 exponent field
    if (e >= 148) atomicOr(&sf, 1);        // |v|>=2^20: impossible for real bf16 weights
  }
  __syncthreads();
  const bool isf32 = (sf != 0);
  if (blockIdx.x == 0 && tid == 0) *flag = sf;

  int stride = gridDim.x * blockDim.x;
  int t0 = blockIdx.x * blockDim.x + tid;
  for (int s = 0; s < 14; ++s){
    const void* src = a.src[s];
    int n = a.n[s];
    float* dst = params + a.off[s];
    if (isf32){
      const float* f = (const float*)src;
      for (int i = t0; i < n; i += stride) dst[i] = f[i];
    } else {
      const unsigned short* u = (const unsigned short*)src;
      for (int i = t0; i < n; i += stride) dst[i] = bflo(u[i]);
    }
  }
  // Wt[l][n][k] = conv_W[l][k][n] as bf16, read directly from source
  for (int idx = t0; idx < NLAYERS * 65536; idx += stride){
    int l = idx >> 16, rem = idx & 65535, n = rem >> 8, k = rem & 255;
    int si = l * 65536 + k * 256 + n;
    float v = isf32 ? ((const float*)a.convw)[si] : bflo(((const unsigned short*)a.convw)[si]);
    Wt[idx] = f2bf(v);
  }
}

__global__ void k_init(int* __restrict__ deg, int* __restrict__ fill,
                       float* __restrict__ pooled, float* __restrict__ counts){
  int i = blockIdx.x * blockDim.x + threadIdx.x;
  if (i < N_NODES){ deg[i] = 1; fill[i] = 0; }       // self-loop contributes 1
  if (i < NGRAPHS * 256) pooled[i] = 0.f;
  if (i < NGRAPHS) counts[i] = 0.f;
}

__global__ void k_deg(const int* __restrict__ dst, int* __restrict__ deg){
  int e = blockIdx.x * blockDim.x + threadIdx.x;
  if (e < N_EDGES) atomicAdd(&deg[dst[e]], 1);
}

// ---- hierarchical exclusive scan of deg -> row_start (+ fused dinv) ----
__global__ __launch_bounds__(256) void k_scan1(const int* __restrict__ deg, int* __restrict__ row_start,
                                               int* __restrict__ bsum, float* __restrict__ dinv){
  __shared__ int sd[256];
  int tid = threadIdx.x;
  int i = blockIdx.x * 256 + tid;
  int v = (i < N_NODES) ? deg[i] : 0;
  if (i < N_NODES) dinv[i] = rsqrtf((float)v);
  sd[tid] = v;
  __syncthreads();
#pragma unroll
  for (int off = 1; off < 256; off <<= 1){
    int t = (tid >= off) ? sd[tid - off] : 0;
    __syncthreads();
    sd[tid] += t;
    __syncthreads();
  }
  if (i < N_NODES) row_start[i] = sd[tid];
  if (tid == 255) bsum[blockIdx.x] = sd[255];
}

__global__ __launch_bounds__(256) void k_scan2(const int* __restrict__ bsum, int* __restrict__ boff,
                                               int* __restrict__ row_start){
  __shared__ int sd[256];
  int tid = threadIdx.x;
  int v = (tid < NSCANBLK) ? bsum[tid] : 0;
  sd[tid] = v;
  __syncthreads();
#pragma unroll
  for (int off = 1; off < 256; off <<= 1){
    int t = (tid >= off) ? sd[tid - off] : 0;
    __syncthreads();
    sd[tid] += t;
    __syncthreads();
  }
  if (tid < NSCANBLK) boff[tid] = sd[tid] - v;   // exclusive
  if (tid == NSCANBLK - 1) row_start[N_NODES] = sd[tid];
}

__global__ __launch_bounds__(256) void k_scan3(const int* __restrict__ deg, const int* __restrict__ boff,
                                               int* __restrict__ row_start){
  int i = blockIdx.x * 256 + threadIdx.x;
  if (i < N_NODES) row_start[i] = row_start[i] + boff[blockIdx.x] - deg[i];
}

__global__ void k_fill(const int* __restrict__ src, const int* __restrict__ dst,
                       const int* __restrict__ row_start, int* __restrict__ fill,
                       const float* __restrict__ dinv,
                       int* __restrict__ csr_src, float* __restrict__ csr_w){
  int t = blockIdx.x * blockDim.x + threadIdx.x;
  if (t >= N_EDGES + N_NODES) return;
  int s, d;
  if (t < N_EDGES){ s = src[t]; d = dst[t]; }
  else            { s = t - N_EDGES; d = s; }      // self loops
  int pos = row_start[d] + atomicAdd(&fill[d], 1);
  csr_src[pos] = s;
  csr_w[pos] = dinv[s] * dinv[d];
}

// input projection: Linear(3,256) -> ReLU -> GroupNorm(1,256). one wave per node. bf16 out.
__global__ __launch_bounds__(256) void k_input_proj(const float* __restrict__ params,
                                                    ushort* __restrict__ x_bf){
  int lane = threadIdx.x & 63;
  int node = (blockIdx.x << 2) + (threadIdx.x >> 6);
  if (node >= N_NODES) return;
  const float* pos = params + OFF_POS + node * 3;
  float px = pos[0], py = pos[1], pz = pos[2];
  int c = lane * 4;
  const float* w0 = params + OFF_WIN;
  float v[4];
#pragma unroll
  for (int j = 0; j < 4; ++j){
    float t = params[OFF_BIN + c + j];
    t = fmaf(px, w0[c + j], t);
    t = fmaf(py, w0[256 + c + j], t);
    t = fmaf(pz, w0[512 + c + j], t);
    v[j] = fmaxf(t, 0.f);
  }
  float s  = v[0] + v[1] + v[2] + v[3];
  float ss = v[0]*v[0] + v[1]*v[1] + v[2]*v[2] + v[3]*v[3];
  s = wave_reduce_sum(s); ss = wave_reduce_sum(ss);
  float mean = s * (1.f/256.f);
  float var  = ss * (1.f/256.f) - mean * mean;
  float inv  = rsqrtf(var + EPS);
  float4 o;
  o.x = (v[0]-mean)*inv*params[OFF_GIN+c+0] + params[OFF_BEIN+c+0];
  o.y = (v[1]-mean)*inv*params[OFF_GIN+c+1] + params[OFF_BEIN+c+1];
  o.z = (v[2]-mean)*inv*params[OFF_GIN+c+2] + params[OFF_BEIN+c+2];
  o.w = (v[3]-mean)*inv*params[OFF_GIN+c+3] + params[OFF_BEIN+c+3];
  ushort4 ob = { f2bf(o.x), f2bf(o.y), f2bf(o.z), f2bf(o.w) };
  *(ushort4*)(x_bf + node * 256 + c) = ob;
}

// bf16 MFMA GEMM: Cb(Mx256 bf16) = A(Mx256 bf16) @ Wt^T.  Wt is [n][k].
#define GBM 128
#define LDK 72
__global__ __launch_bounds__(256) void k_gemm_bf(const ushort* __restrict__ A, const ushort* __restrict__ Bt,
                                                 ushort* __restrict__ Cb, int M){
  __shared__ __align__(16) ushort As[GBM][LDK];
  __shared__ __align__(16) ushort Bs[GBM][LDK];
  int tid = threadIdx.x;
  int wave = tid >> 6, lane = tid & 63;
  int wr = wave >> 1, wc = wave & 1;
  int row0 = blockIdx.y * GBM;
  int col0 = blockIdx.x * GBM;
  int q = lane >> 4, l15 = lane & 15;
  floatx4 acc[4][4] = {};
  for (int k0 = 0; k0 < 256; k0 += 64){
    __syncthreads();
#pragma unroll
    for (int i = 0; i < 4; ++i){
      int idx = tid + i * 256;
      int r = idx >> 3, seg = idx & 7;
      int gr = row0 + r;
      uint4 av = {0,0,0,0};
      if (gr < M) av = *(const uint4*)(A + gr * 256 + k0 + seg * 8);
      *(uint4*)&As[r][seg * 8] = av;
      uint4 bv = *(const uint4*)(Bt + (col0 + r) * 256 + k0 + seg * 8);
      *(uint4*)&Bs[r][seg * 8] = bv;
    }
    __syncthreads();
#pragma unroll
    for (int kk = 0; kk < 64; kk += 32){
      short8 af[4], bfr[4];
#pragma unroll
      for (int i = 0; i < 4; ++i)
        af[i] = *(const short8*)&As[wr * 64 + i * 16 + l15][kk + q * 8];
#pragma unroll
      for (int j = 0; j < 4; ++j)
        bfr[j] = *(const short8*)&Bs[wc * 64 + j * 16 + l15][kk + q * 8];
#pragma unroll
      for (int i = 0; i < 4; ++i)
#pragma unroll
        for (int j = 0; j < 4; ++j)
          acc[i][j] = __builtin_amdgcn_mfma_f32_16x16x32_bf16(af[i], bfr[j], acc[i][j], 0, 0, 0);
    }
  }
#pragma unroll
  for (int i = 0; i < 4; ++i){
#pragma unroll
    for (int r = 0; r < 4; ++r){
      int row = row0 + wr * 64 + i * 16 + q * 4 + r;
      if (row < M){
#pragma unroll
        for (int j = 0; j < 4; ++j){
          int col = col0 + wc * 64 + j * 16 + l15;
          Cb[row * 256 + col] = f2bf(acc[i][j][r]);
        }
      }
    }
  }
}

// aggregate over CSR (bf16 h) + bias + GroupNorm + ReLU + residual (bf16 x, in-place).
// one wave per node; 4-wide index prefetch to overlap gather latency.
__global__ __launch_bounds__(256) void k_agg_norm(const ushort* __restrict__ hb, ushort* __restrict__ x_bf,
    const int* __restrict__ row_start, const int* __restrict__ csr_src, const float* __restrict__ csr_w,
    const float* __restrict__ params, int layer){
  int lane = threadIdx.x & 63;
  int node = (blockIdx.x << 2) + (threadIdx.x >> 6);
  if (node >= N_NODES) return;
  int c = lane * 4;
  float a0 = 0.f, a1 = 0.f, a2 = 0.f, a3 = 0.f;
  int p0 = row_start[node], p1 = row_start[node + 1];
  int p = p0;
  for (; p + 4 <= p1; p += 4){
    int s0 = csr_src[p],     s1 = csr_src[p + 1];
    int s2 = csr_src[p + 2], s3 = csr_src[p + 3];
    float w0 = csr_w[p],     w1 = csr_w[p + 1];
    float w2 = csr_w[p + 2], w3 = csr_w[p + 3];
    uint2 v0 = *(const uint2*)(hb + (size_t)s0 * 256 + c);
    uint2 v1 = *(const uint2*)(hb + (size_t)s1 * 256 + c);
    uint2 v2 = *(const uint2*)(hb + (size_t)s2 * 256 + c);
    uint2 v3 = *(const uint2*)(hb + (size_t)s3 * 256 + c);
    a0 = fmaf(w0, bflo(v0.x), a0); a1 = fmaf(w0, bfhi(v0.x), a1);
    a2 = fmaf(w0, bflo(v0.y), a2); a3 = fmaf(w0, bfhi(v0.y), a3);
    a0 = fmaf(w1, bflo(v1.x), a0); a1 = fmaf(w1, bfhi(v1.x), a1);
    a2 = fmaf(w1, bflo(v1.y), a2); a3 = fmaf(w1, bfhi(v1.y), a3);
    a0 = fmaf(w2, bflo(v2.x), a0); a1 = fmaf(w2, bfhi(v2.x), a1);
    a2 = fmaf(w2, bflo(v2.y), a2); a3 = fmaf(w2, bfhi(v2.y), a3);
    a0 = fmaf(w3, bflo(v3.x), a0); a1 = fmaf(w3, bfhi(v3.x), a1);
    a2 = fmaf(w3, bflo(v3.y), a2); a3 = fmaf(w3, bfhi(v3.y), a3);
  }
  for (; p < p1; ++p){
    int s0 = csr_src[p];
    float w0 = csr_w[p];
    uint2 v0 = *(const uint2*)(hb + (size_t)s0 * 256 + c);
    a0 = fmaf(w0, bflo(v0.x), a0); a1 = fmaf(w0, bfhi(v0.x), a1);
    a2 = fmaf(w0, bflo(v0.y), a2); a3 = fmaf(w0, bfhi(v0.y), a3);
  }
  const float* cb = params + OFF_CONVB + layer * 256;
  float v[4] = { a0 + cb[c], a1 + cb[c+1], a2 + cb[c+2], a3 + cb[c+3] };
  float s  = v[0] + v[1] + v[2] + v[3];
  float ss = v[0]*v[0] + v[1]*v[1] + v[2]*v[2] + v[3]*v[3];
  s = wave_reduce_sum(s); ss = wave_reduce_sum(ss);
  float mean = s * (1.f/256.f);
  float var  = ss * (1.f/256.f) - mean * mean;
  float inv  = rsqrtf(var + EPS);
  const float* g = params + OFF_GNG + layer * 256;
  const float* b = params + OFF_GNB + layer * 256;
  uint2 xo = *(uint2*)(x_bf + (size_t)node * 256 + c);
  float o0 = fmaxf((v[0]-mean)*inv*g[c+0] + b[c+0], 0.f) + bflo(xo.x);
  float o1 = fmaxf((v[1]-mean)*inv*g[c+1] + b[c+1], 0.f) + bfhi(xo.x);
  float o2 = fmaxf((v[2]-mean)*inv*g[c+2] + b[c+2], 0.f) + bflo(xo.y);
  float o3 = fmaxf((v[3]-mean)*inv*g[c+3] + b[c+3], 0.f) + bfhi(xo.y);
  ushort4 ob = { f2bf(o0), f2bf(o1), f2bf(o2), f2bf(o3) };
  *(ushort4*)(x_bf + (size_t)node * 256 + c) = ob;
}

// global mean pool over bf16 x: wave owns 16 nodes; boundary check hoisted; fast path unrolled 4-wide.
__global__ __launch_bounds__(256) void k_pool(const ushort* __restrict__ x_bf, const int* __restrict__ batch,
                                              float* __restrict__ pooled, float* __restrict__ counts){
  int tid = threadIdx.x;
  int wave = tid >> 6, lane = tid & 63;
  int c = lane * 4;
  int n0 = blockIdx.x * 64 + wave * 16;
  if (n0 >= N_NODES) return;
  int n1 = min(n0 + 16, N_NODES);
  int b0 = batch[n0], b1 = batch[n1 - 1];
  float a0 = 0.f, a1 = 0.f, a2 = 0.f, a3 = 0.f;
  if (b0 == b1){                              // wave-uniform fast path (~99.5% of waves)
    int i = n0;
    for (; i + 4 <= n1; i += 4){
      uint2 v0 = *(const uint2*)(x_bf + (size_t)(i + 0) * 256 + c);
      uint2 v1 = *(const uint2*)(x_bf + (size_t)(i + 1) * 256 + c);
      uint2 v2 = *(const uint2*)(x_bf + (size_t)(i + 2) * 256 + c);
      uint2 v3 = *(const uint2*)(x_bf + (size_t)(i + 3) * 256 + c);
      a0 += bflo(v0.x) + bflo(v1.x) + bflo(v2.x) + bflo(v3.x);
      a1 += bfhi(v0.x) + bfhi(v1.x) + bfhi(v2.x) + bfhi(v3.x);
      a2 += bflo(v0.y) + bflo(v1.y) + bflo(v2.y) + bflo(v3.y);
      a3 += bfhi(v0.y) + bfhi(v1.y) + bfhi(v2.y) + bfhi(v3.y);
    }
    for (; i < n1; ++i){
      uint2 v = *(const uint2*)(x_bf + (size_t)i * 256 + c);
      a0 += bflo(v.x); a1 += bfhi(v.x); a2 += bflo(v.y); a3 += bfhi(v.y);
    }
    float* p = pooled + b0 * 256 + c;
    atomicAdd(p + 0, a0); atomicAdd(p + 1, a1);
    atomicAdd(p + 2, a2); atomicAdd(p + 3, a3);
    if (lane == 0) atomicAdd(&counts[b0], (float)(n1 - n0));
  } else {                                    // boundary wave: per-node flush logic
    int cur = b0, cnt = 0;
    for (int i = n0; i < n1; ++i){
      int g = batch[i];
      if (g != cur){
        float* p = pooled + cur * 256 + c;
        atomicAdd(p + 0, a0); atomicAdd(p + 1, a1);
        atomicAdd(p + 2, a2); atomicAdd(p + 3, a3);
        if (lane == 0) atomicAdd(&counts[cur], (float)cnt);
        a0 = a1 = a2 = a3 = 0.f; cnt = 0; cur = g;
      }
      uint2 v = *(const uint2*)(x_bf + (size_t)i * 256 + c);
      a0 += bflo(v.x); a1 += bfhi(v.x); a2 += bflo(v.y); a3 += bfhi(v.y);
      cnt++;
    }
    float* p = pooled + cur * 256 + c;
    atomicAdd(p + 0, a0); atomicAdd(p + 1, a1);
    atomicAdd(p + 2, a2); atomicAdd(p + 3, a3);
    if (lane == 0) atomicAdd(&counts[cur], (float)cnt);
  }
}

__global__ __launch_bounds__(256) void k_head(const float* __restrict__ pooled, const float* __restrict__ counts,
    const float* __restrict__ params, void* __restrict__ out, const int* __restrict__ flag){
  __shared__ float m[256];
  __shared__ float hh[256];
  __shared__ float red[2][4];
  int g = blockIdx.x, tid = threadIdx.x;
  float cnt = fmaxf(counts[g], 1.f);
  m[tid] = pooled[g * 256 + tid] / cnt;
  __syncthreads();
  const float* W1 = params + OFF_WO1;
  float acc = params[OFF_BO1 + tid];
  for (int k = 0; k < 256; ++k) acc = fmaf(m[k], W1[k * 256 + tid], acc);
  acc = fmaxf(acc, 0.f);
  float s = wave_reduce_sum(acc), ss = wave_reduce_sum(acc * acc);
  int wv = tid >> 6, lane = tid & 63;
  if (lane == 0){ red[0][wv] = s; red[1][wv] = ss; }
  __syncthreads();
  float S  = red[0][0] + red[0][1] + red[0][2] + red[0][3];
  float SS = red[1][0] + red[1][1] + red[1][2] + red[1][3];
  float mean = S * (1.f/256.f);
  float var  = SS * (1.f/256.f) - mean * mean;
  float inv  = rsqrtf(var + EPS);
  float hn = (acc - mean) * inv * params[OFF_GO + tid] + params[OFF_BEO + tid];
  hh[tid] = hn;
  __syncthreads();
  if (tid < ZDIM){
    const float* W2 = params + OFF_WO2;
    float o = params[OFF_BO2 + tid];
    for (int k = 0; k < 256; ++k) o = fmaf(hh[k], W2[k * 128 + tid], o);
    if (*flag) ((float*)out)[g * 128 + tid] = o;
    else       ((__hip_bfloat16*)out)[g * 128 + tid] = __float2bfloat16(o);
  }
}

extern "C" void kernel_launch(void* const* d_in, const int* in_sizes, int n_in,
                              void* d_out, int out_size, void* d_ws, size_t ws_size,
                              hipStream_t stream){
  // ---- workspace layout ----
  size_t o = 0;
  auto alloc = [&](size_t bytes)->size_t{ size_t r = o; o = (o + bytes + 255) & ~(size_t)255; return r; };
  size_t off_flag   = alloc(4);
  size_t off_deg    = alloc((size_t)N_NODES * 4);
  size_t off_dinv   = alloc((size_t)N_NODES * 4);
  size_t off_rs     = alloc((size_t)(N_NODES + 1) * 4);
  size_t off_fill   = alloc((size_t)N_NODES * 4);
  size_t off_bsum   = alloc((size_t)NSCANBLK * 4);
  size_t off_boff   = alloc((size_t)NSCANBLK * 4);
  size_t off_csrs   = alloc((size_t)(N_EDGES + N_NODES) * 4);
  size_t off_csrw   = alloc((size_t)(N_EDGES + N_NODES) * 4);
  size_t off_params = alloc((size_t)PARAMS_TOTAL * 4);
  size_t off_xbf    = alloc((size_t)N_NODES * HIDDEN * 2);
  size_t off_hbf    = alloc((size_t)N_NODES * HIDDEN * 2);
  size_t off_wt     = alloc((size_t)NLAYERS * HIDDEN * HIDDEN * 2);
  size_t off_pool   = alloc((size_t)NGRAPHS * 256 * 4);
  size_t off_cnt    = alloc((size_t)NGRAPHS * 4);
  if (o > ws_size) return;

  char* ws = (char*)d_ws;
  int*    flag     = (int*)(ws + off_flag);
  int*    deg      = (int*)(ws + off_deg);
  float*  dinv     = (float*)(ws + off_dinv);
  int*    row_start= (int*)(ws + off_rs);
  int*    fill     = (int*)(ws + off_fill);
  int*    bsum     = (int*)(ws + off_bsum);
  int*    boff     = (int*)(ws + off_boff);
  int*    csr_src  = (int*)(ws + off_csrs);
  float*  csr_w    = (float*)(ws + off_csrw);
  float*  params   = (float*)(ws + off_params);
  ushort* x_bf     = (ushort*)(ws + off_xbf);
  ushort* h_bf     = (ushort*)(ws + off_hbf);
  ushort* Wt       = (ushort*)(ws + off_wt);
  float*  pooled   = (float*)(ws + off_pool);
  float*  counts   = (float*)(ws + off_cnt);

  const int* edge_src = (const int*)d_in[1];               // edge_index[0]
  const int* edge_dst = (const int*)d_in[1] + N_EDGES;     // edge_index[1]
  const int* batch    = (const int*)d_in[2];

  // ---- fused dtype detect + param convert + Wt build ----
  PrepArgs pa;
  const int srcIdx[14] = {0,3,4,5,6,8,9,10,11,12,13,14,15,16};
  const int ns[14]     = {150000,768,256,256,256,768,768,768,65536,256,256,256,32768,128};
  const int offs[14]   = {OFF_POS,OFF_WIN,OFF_BIN,OFF_GIN,OFF_BEIN,OFF_CONVB,OFF_GNG,OFF_GNB,
                          OFF_WO1,OFF_BO1,OFF_GO,OFF_BEO,OFF_WO2,OFF_BO2};
  for (int i = 0; i < 14; ++i){ pa.src[i] = d_in[srcIdx[i]]; pa.n[i] = ns[i]; pa.off[i] = offs[i]; }
  pa.win = d_in[3]; pa.convw = d_in[7];
  k_prep<<<512, 256, 0, stream>>>(pa, params, Wt, flag);

  // ---- graph preprocessing ----
  k_init<<<(N_NODES + 255) / 256, 256, 0, stream>>>(deg, fill, pooled, counts);
  k_deg<<<(N_EDGES + 255) / 256, 256, 0, stream>>>(edge_dst, deg);
  k_scan1<<<NSCANBLK, 256, 0, stream>>>(deg, row_start, bsum, dinv);
  k_scan2<<<1, 256, 0, stream>>>(bsum, boff, row_start);
  k_scan3<<<NSCANBLK, 256, 0, stream>>>(deg, boff, row_start);
  k_fill<<<(N_EDGES + N_NODES + 255) / 256, 256, 0, stream>>>(edge_src, edge_dst, row_start, fill,
                                                              dinv, csr_src, csr_w);
  // ---- input projection ----
  k_input_proj<<<N_NODES / 4, 256, 0, stream>>>(params, x_bf);

  // ---- GCN layers ----
  dim3 ggrid(2, (N_NODES + GBM - 1) / GBM);
  for (int l = 0; l < NLAYERS; ++l){
    k_gemm_bf<<<ggrid, 256, 0, stream>>>(x_bf, Wt + l * 65536, h_bf, N_NODES);
    k_agg_norm<<<N_NODES / 4, 256, 0, stream>>>(h_bf, x_bf, row_start, csr_src, csr_w, params, l);
  }

  // ---- pool + head ----
  k_pool<<<(N_NODES + 63) / 64, 256, 0, stream>>>(x_bf, batch, pooled, counts);
  k_head<<<NGRAPHS, 256, 0, stream>>>(pooled, counts, params, d_out, flag);
}

// Round 6
// 370.347 us; speedup vs baseline: 2.1299x; 1.0719x over previous
//
#include <hip/hip_runtime.h>
#include <hip/hip_bf16.h>

#define N_NODES 50000
#define N_EDGES 300000
#define HIDDEN 256
#define ZDIM 128
#define NLAYERS 3
#define NGRAPHS 16
#define EPS 1e-5f
#define NSCANBLK 196   // ceil(50000/256)

// ---- fp32 param region offsets (floats) ----
#define OFF_POS    0
#define OFF_WIN    150000
#define OFF_BIN    150768
#define OFF_GIN    151024
#define OFF_BEIN   151280
#define OFF_CONVB  348144
#define OFF_GNG    348912
#define OFF_GNB    349680
#define OFF_WO1    350448
#define OFF_BO1    415984
#define OFF_GO     416240
#define OFF_BEO    416496
#define OFF_WO2    416752
#define OFF_BO2    449520
#define PARAMS_TOTAL 449648

typedef __attribute__((ext_vector_type(8))) short short8;
typedef __attribute__((ext_vector_type(4))) float floatx4;

__device__ inline float wave_reduce_sum(float v){
#pragma unroll
  for (int off = 32; off; off >>= 1) v += __shfl_xor(v, off);
  return v;
}

__device__ inline ushort f2bf(float f){
  __hip_bfloat16 t = __float2bfloat16(f);
  return *(ushort*)&t;
}
__device__ inline float bflo(unsigned int u){ return __uint_as_float(u << 16); }
__device__ inline float bfhi(unsigned int u){ return __uint_as_float(u & 0xffff0000u); }

struct PrepArgs { const void* src[14]; int n[14]; int off[14]; const void* win; const void* convw; };

// fused: per-block dtype detect + param convert (14 tensors) + Wt build (transposed bf16 conv_W)
__global__ __launch_bounds__(256) void k_prep(PrepArgs a, float* __restrict__ params,
                                              ushort* __restrict__ Wt, int* __restrict__ flag){
  __shared__ int sf;
  int tid = threadIdx.x;
  if (tid == 0) sf = 0;
  __syncthreads();
  const unsigned short* w = (const unsigned short*)a.win;
  for (int i = tid; i < 768; i += 256){
    int e = (w[i] >> 7) & 0xff;            // bf16 exponent field
    if (e >= 148) atomicOr(&sf, 1);        // |v|>=2^20: impossible for real bf16 weights
  }
  __syncthreads();
  const bool isf32 = (sf != 0);
  if (blockIdx.x == 0 && tid == 0) *flag = sf;

  int stride = gridDim.x * blockDim.x;
  int t0 = blockIdx.x * blockDim.x + tid;
  for (int s = 0; s < 14; ++s){
    const void* src = a.src[s];
    int n = a.n[s];
    float* dst = params + a.off[s];
    if (isf32){
      const float* f = (const float*)src;
      for (int i = t0; i < n; i += stride) dst[i] = f[i];
    } else {
      const unsigned short* u = (const unsigned short*)src;
      for (int i = t0; i < n; i += stride) dst[i] = bflo(u[i]);
    }
  }
  // Wt[l][n][k] = conv_W[l][k][n] as bf16, read directly from source
  for (int idx = t0; idx < NLAYERS * 65536; idx += stride){
    int l = idx >> 16, rem = idx & 65535, n = rem >> 8, k = rem & 255;
    int si = l * 65536 + k * 256 + n;
    float v = isf32 ? ((const float*)a.convw)[si] : bflo(((const unsigned short*)a.convw)[si]);
    Wt[idx] = f2bf(v);
  }
}

__global__ void k_init(int* __restrict__ deg, int* __restrict__ fill,
                       float* __restrict__ pooled, float* __restrict__ counts){
  int i = blockIdx.x * blockDim.x + threadIdx.x;
  if (i < N_NODES){ deg[i] = 1; fill[i] = 0; }       // self-loop contributes 1
  if (i < NGRAPHS * 256) pooled[i] = 0.f;
  if (i < NGRAPHS) counts[i] = 0.f;
}

__global__ void k_deg(const int* __restrict__ dst, int* __restrict__ deg){
  int e = blockIdx.x * blockDim.x + threadIdx.x;
  if (e < N_EDGES) atomicAdd(&deg[dst[e]], 1);
}

// ---- hierarchical exclusive scan of deg -> row_start (+ fused dinv) ----
__global__ __launch_bounds__(256) void k_scan1(const int* __restrict__ deg, int* __restrict__ row_start,
                                               int* __restrict__ bsum, float* __restrict__ dinv){
  __shared__ int sd[256];
  int tid = threadIdx.x;
  int i = blockIdx.x * 256 + tid;
  int v = (i < N_NODES) ? deg[i] : 0;
  if (i < N_NODES) dinv[i] = rsqrtf((float)v);
  sd[tid] = v;
  __syncthreads();
#pragma unroll
  for (int off = 1; off < 256; off <<= 1){
    int t = (tid >= off) ? sd[tid - off] : 0;
    __syncthreads();
    sd[tid] += t;
    __syncthreads();
  }
  if (i < N_NODES) row_start[i] = sd[tid];
  if (tid == 255) bsum[blockIdx.x] = sd[255];
}

__global__ __launch_bounds__(256) void k_scan2(const int* __restrict__ bsum, int* __restrict__ boff,
                                               int* __restrict__ row_start){
  __shared__ int sd[256];
  int tid = threadIdx.x;
  int v = (tid < NSCANBLK) ? bsum[tid] : 0;
  sd[tid] = v;
  __syncthreads();
#pragma unroll
  for (int off = 1; off < 256; off <<= 1){
    int t = (tid >= off) ? sd[tid - off] : 0;
    __syncthreads();
    sd[tid] += t;
    __syncthreads();
  }
  if (tid < NSCANBLK) boff[tid] = sd[tid] - v;   // exclusive
  if (tid == NSCANBLK - 1) row_start[N_NODES] = sd[tid];
}

__global__ __launch_bounds__(256) void k_scan3(const int* __restrict__ deg, const int* __restrict__ boff,
                                               int* __restrict__ row_start){
  int i = blockIdx.x * 256 + threadIdx.x;
  if (i < N_NODES) row_start[i] = row_start[i] + boff[blockIdx.x] - deg[i];
}

__global__ void k_fill(const int* __restrict__ src, const int* __restrict__ dst,
                       const int* __restrict__ row_start, int* __restrict__ fill,
                       const float* __restrict__ dinv,
                       int* __restrict__ csr_src, float* __restrict__ csr_w){
  int t = blockIdx.x * blockDim.x + threadIdx.x;
  if (t >= N_EDGES + N_NODES) return;
  int s, d;
  if (t < N_EDGES){ s = src[t]; d = dst[t]; }
  else            { s = t - N_EDGES; d = s; }      // self loops
  int pos = row_start[d] + atomicAdd(&fill[d], 1);
  csr_src[pos] = s;
  csr_w[pos] = dinv[s] * dinv[d];
}

// input projection: Linear(3,256) -> ReLU -> GroupNorm(1,256). one wave per node. bf16 out.
__global__ __launch_bounds__(256) void k_input_proj(const float* __restrict__ params,
                                                    ushort* __restrict__ x_bf){
  int lane = threadIdx.x & 63;
  int node = (blockIdx.x << 2) + (threadIdx.x >> 6);
  if (node >= N_NODES) return;
  const float* pos = params + OFF_POS + node * 3;
  float px = pos[0], py = pos[1], pz = pos[2];
  int c = lane * 4;
  const float* w0 = params + OFF_WIN;
  float v[4];
#pragma unroll
  for (int j = 0; j < 4; ++j){
    float t = params[OFF_BIN + c + j];
    t = fmaf(px, w0[c + j], t);
    t = fmaf(py, w0[256 + c + j], t);
    t = fmaf(pz, w0[512 + c + j], t);
    v[j] = fmaxf(t, 0.f);
  }
  float s  = v[0] + v[1] + v[2] + v[3];
  float ss = v[0]*v[0] + v[1]*v[1] + v[2]*v[2] + v[3]*v[3];
  s = wave_reduce_sum(s); ss = wave_reduce_sum(ss);
  float mean = s * (1.f/256.f);
  float var  = ss * (1.f/256.f) - mean * mean;
  float inv  = rsqrtf(var + EPS);
  float4 o;
  o.x = (v[0]-mean)*inv*params[OFF_GIN+c+0] + params[OFF_BEIN+c+0];
  o.y = (v[1]-mean)*inv*params[OFF_GIN+c+1] + params[OFF_BEIN+c+1];
  o.z = (v[2]-mean)*inv*params[OFF_GIN+c+2] + params[OFF_BEIN+c+2];
  o.w = (v[3]-mean)*inv*params[OFF_GIN+c+3] + params[OFF_BEIN+c+3];
  ushort4 ob = { f2bf(o.x), f2bf(o.y), f2bf(o.z), f2bf(o.w) };
  *(ushort4*)(x_bf + node * 256 + c) = ob;
}

// bf16 MFMA GEMM: Cb(Mx256 bf16) = A(Mx256 bf16) @ Wt^T.  Wt is [n][k].
#define GBM 128
#define LDK 72
__global__ __launch_bounds__(256) void k_gemm_bf(const ushort* __restrict__ A, const ushort* __restrict__ Bt,
                                                 ushort* __restrict__ Cb, int M){
  __shared__ __align__(16) ushort As[GBM][LDK];
  __shared__ __align__(16) ushort Bs[GBM][LDK];
  int tid = threadIdx.x;
  int wave = tid >> 6, lane = tid & 63;
  int wr = wave >> 1, wc = wave & 1;
  int row0 = blockIdx.y * GBM;
  int col0 = blockIdx.x * GBM;
  int q = lane >> 4, l15 = lane & 15;
  floatx4 acc[4][4] = {};
  for (int k0 = 0; k0 < 256; k0 += 64){
    __syncthreads();
#pragma unroll
    for (int i = 0; i < 4; ++i){
      int idx = tid + i * 256;
      int r = idx >> 3, seg = idx & 7;
      int gr = row0 + r;
      uint4 av = {0,0,0,0};
      if (gr < M) av = *(const uint4*)(A + gr * 256 + k0 + seg * 8);
      *(uint4*)&As[r][seg * 8] = av;
      uint4 bv = *(const uint4*)(Bt + (col0 + r) * 256 + k0 + seg * 8);
      *(uint4*)&Bs[r][seg * 8] = bv;
    }
    __syncthreads();
#pragma unroll
    for (int kk = 0; kk < 64; kk += 32){
      short8 af[4], bfr[4];
#pragma unroll
      for (int i = 0; i < 4; ++i)
        af[i] = *(const short8*)&As[wr * 64 + i * 16 + l15][kk + q * 8];
#pragma unroll
      for (int j = 0; j < 4; ++j)
        bfr[j] = *(const short8*)&Bs[wc * 64 + j * 16 + l15][kk + q * 8];
#pragma unroll
      for (int i = 0; i < 4; ++i)
#pragma unroll
        for (int j = 0; j < 4; ++j)
          acc[i][j] = __builtin_amdgcn_mfma_f32_16x16x32_bf16(af[i], bfr[j], acc[i][j], 0, 0, 0);
    }
  }
#pragma unroll
  for (int i = 0; i < 4; ++i){
#pragma unroll
    for (int r = 0; r < 4; ++r){
      int row = row0 + wr * 64 + i * 16 + q * 4 + r;
      if (row < M){
#pragma unroll
        for (int j = 0; j < 4; ++j){
          int col = col0 + wc * 64 + j * 16 + l15;
          Cb[row * 256 + col] = f2bf(acc[i][j][r]);
        }
      }
    }
  }
}

// aggregate over CSR (bf16 h) + bias + GroupNorm + ReLU + residual (bf16 x, in-place).
__global__ __launch_bounds__(256) void k_agg_norm(const ushort* __restrict__ hb, ushort* __restrict__ x_bf,
    const int* __restrict__ row_start, const int* __restrict__ csr_src, const float* __restrict__ csr_w,
    const float* __restrict__ params, int layer){
  int lane = threadIdx.x & 63;
  int node = (blockIdx.x << 2) + (threadIdx.x >> 6);
  if (node >= N_NODES) return;
  int c = lane * 4;
  float a0 = 0.f, a1 = 0.f, a2 = 0.f, a3 = 0.f;
  int p0 = row_start[node], p1 = row_start[node + 1];
  int p = p0;
  for (; p + 4 <= p1; p += 4){
    int s0 = csr_src[p],     s1 = csr_src[p + 1];
    int s2 = csr_src[p + 2], s3 = csr_src[p + 3];
    float w0 = csr_w[p],     w1 = csr_w[p + 1];
    float w2 = csr_w[p + 2], w3 = csr_w[p + 3];
    uint2 v0 = *(const uint2*)(hb + (size_t)s0 * 256 + c);
    uint2 v1 = *(const uint2*)(hb + (size_t)s1 * 256 + c);
    uint2 v2 = *(const uint2*)(hb + (size_t)s2 * 256 + c);
    uint2 v3 = *(const uint2*)(hb + (size_t)s3 * 256 + c);
    a0 = fmaf(w0, bflo(v0.x), a0); a1 = fmaf(w0, bfhi(v0.x), a1);
    a2 = fmaf(w0, bflo(v0.y), a2); a3 = fmaf(w0, bfhi(v0.y), a3);
    a0 = fmaf(w1, bflo(v1.x), a0); a1 = fmaf(w1, bfhi(v1.x), a1);
    a2 = fmaf(w1, bflo(v1.y), a2); a3 = fmaf(w1, bfhi(v1.y), a3);
    a0 = fmaf(w2, bflo(v2.x), a0); a1 = fmaf(w2, bfhi(v2.x), a1);
    a2 = fmaf(w2, bflo(v2.y), a2); a3 = fmaf(w2, bfhi(v2.y), a3);
    a0 = fmaf(w3, bflo(v3.x), a0); a1 = fmaf(w3, bfhi(v3.x), a1);
    a2 = fmaf(w3, bflo(v3.y), a2); a3 = fmaf(w3, bfhi(v3.y), a3);
  }
  for (; p < p1; ++p){
    int s0 = csr_src[p];
    float w0 = csr_w[p];
    uint2 v0 = *(const uint2*)(hb + (size_t)s0 * 256 + c);
    a0 = fmaf(w0, bflo(v0.x), a0); a1 = fmaf(w0, bfhi(v0.x), a1);
    a2 = fmaf(w0, bflo(v0.y), a2); a3 = fmaf(w0, bfhi(v0.y), a3);
  }
  const float* cb = params + OFF_CONVB + layer * 256;
  float v[4] = { a0 + cb[c], a1 + cb[c+1], a2 + cb[c+2], a3 + cb[c+3] };
  float s  = v[0] + v[1] + v[2] + v[3];
  float ss = v[0]*v[0] + v[1]*v[1] + v[2]*v[2] + v[3]*v[3];
  s = wave_reduce_sum(s); ss = wave_reduce_sum(ss);
  float mean = s * (1.f/256.f);
  float var  = ss * (1.f/256.f) - mean * mean;
  float inv  = rsqrtf(var + EPS);
  const float* g = params + OFF_GNG + layer * 256;
  const float* b = params + OFF_GNB + layer * 256;
  uint2 xo = *(uint2*)(x_bf + (size_t)node * 256 + c);
  float o0 = fmaxf((v[0]-mean)*inv*g[c+0] + b[c+0], 0.f) + bflo(xo.x);
  float o1 = fmaxf((v[1]-mean)*inv*g[c+1] + b[c+1], 0.f) + bfhi(xo.x);
  float o2 = fmaxf((v[2]-mean)*inv*g[c+2] + b[c+2], 0.f) + bflo(xo.y);
  float o3 = fmaxf((v[3]-mean)*inv*g[c+3] + b[c+3], 0.f) + bfhi(xo.y);
  ushort4 ob = { f2bf(o0), f2bf(o1), f2bf(o2), f2bf(o3) };
  *(ushort4*)(x_bf + (size_t)node * 256 + c) = ob;
}

// global mean pool v4: 196 blocks x 256 nodes; wave owns 64 nodes, 8-deep load unroll;
// LDS [16][256] block accumulator (LDS atomics, <=4-way); one global-atomic row flush per
// graph present in the block (~1.3 rows/block => ~65k global atomics vs 800k before).
#define PBLK 256
__global__ __launch_bounds__(256) void k_pool(const ushort* __restrict__ x_bf, const int* __restrict__ batch,
                                              float* __restrict__ pooled, float* __restrict__ counts){
  __shared__ float lacc[NGRAPHS][256];
  __shared__ float lcnt[NGRAPHS];
  int tid = threadIdx.x;
  int wave = tid >> 6, lane = tid & 63;
  int c = lane * 4;
#pragma unroll
  for (int g = 0; g < NGRAPHS; ++g) lacc[g][tid] = 0.f;
  if (tid < NGRAPHS) lcnt[tid] = 0.f;
  __syncthreads();

  int n0 = blockIdx.x * PBLK + wave * 64;
  if (n0 < N_NODES){
    int n1 = min(n0 + 64, N_NODES);
    int b0 = batch[n0], b1 = batch[n1 - 1];
    float a0 = 0.f, a1 = 0.f, a2 = 0.f, a3 = 0.f;
    if (b0 == b1){                            // wave-uniform fast path
      int i = n0;
      for (; i + 8 <= n1; i += 8){
        uint2 v[8];
#pragma unroll
        for (int j = 0; j < 8; ++j) v[j] = *(const uint2*)(x_bf + (size_t)(i + j) * 256 + c);
#pragma unroll
        for (int j = 0; j < 8; ++j){
          a0 += bflo(v[j].x); a1 += bfhi(v[j].x);
          a2 += bflo(v[j].y); a3 += bfhi(v[j].y);
        }
      }
      for (; i < n1; ++i){
        uint2 v = *(const uint2*)(x_bf + (size_t)i * 256 + c);
        a0 += bflo(v.x); a1 += bfhi(v.x); a2 += bflo(v.y); a3 += bfhi(v.y);
      }
      atomicAdd(&lacc[b0][c + 0], a0); atomicAdd(&lacc[b0][c + 1], a1);
      atomicAdd(&lacc[b0][c + 2], a2); atomicAdd(&lacc[b0][c + 3], a3);
      if (lane == 0) atomicAdd(&lcnt[b0], (float)(n1 - n0));
    } else {                                  // boundary wave (<=15 per launch)
      int cur = b0, cnt = 0;
      for (int i = n0; i < n1; ++i){
        int g = batch[i];
        if (g != cur){
          atomicAdd(&lacc[cur][c + 0], a0); atomicAdd(&lacc[cur][c + 1], a1);
          atomicAdd(&lacc[cur][c + 2], a2); atomicAdd(&lacc[cur][c + 3], a3);
          if (lane == 0) atomicAdd(&lcnt[cur], (float)cnt);
          a0 = a1 = a2 = a3 = 0.f; cnt = 0; cur = g;
        }
        uint2 v = *(const uint2*)(x_bf + (size_t)i * 256 + c);
        a0 += bflo(v.x); a1 += bfhi(v.x); a2 += bflo(v.y); a3 += bfhi(v.y);
        cnt++;
      }
      atomicAdd(&lacc[cur][c + 0], a0); atomicAdd(&lacc[cur][c + 1], a1);
      atomicAdd(&lacc[cur][c + 2], a2); atomicAdd(&lacc[cur][c + 3], a3);
      if (lane == 0) atomicAdd(&lcnt[cur], (float)cnt);
    }
  }
  __syncthreads();

  int base = blockIdx.x * PBLK;
  if (base < N_NODES){
    int gmin = batch[base];
    int gmax = batch[min(base + PBLK, N_NODES) - 1];
    for (int g = gmin; g <= gmax; ++g){
      float v = lacc[g][tid];
      if (v != 0.f) atomicAdd(&pooled[g * 256 + tid], v);
      if (tid == 0 && lcnt[g] > 0.f) atomicAdd(&counts[g], lcnt[g]);
    }
  }
}

__global__ __launch_bounds__(256) void k_head(const float* __restrict__ pooled, const float* __restrict__ counts,
    const float* __restrict__ params, void* __restrict__ out, const int* __restrict__ flag){
  __shared__ float m[256];
  __shared__ float hh[256];
  __shared__ float red[2][4];
  int g = blockIdx.x, tid = threadIdx.x;
  float cnt = fmaxf(counts[g], 1.f);
  m[tid] = pooled[g * 256 + tid] / cnt;
  __syncthreads();
  const float* W1 = params + OFF_WO1;
  float acc = params[OFF_BO1 + tid];
  for (int k = 0; k < 256; ++k) acc = fmaf(m[k], W1[k * 256 + tid], acc);
  acc = fmaxf(acc, 0.f);
  float s = wave_reduce_sum(acc), ss = wave_reduce_sum(acc * acc);
  int wv = tid >> 6, lane = tid & 63;
  if (lane == 0){ red[0][wv] = s; red[1][wv] = ss; }
  __syncthreads();
  float S  = red[0][0] + red[0][1] + red[0][2] + red[0][3];
  float SS = red[1][0] + red[1][1] + red[1][2] + red[1][3];
  float mean = S * (1.f/256.f);
  float var  = SS * (1.f/256.f) - mean * mean;
  float inv  = rsqrtf(var + EPS);
  float hn = (acc - mean) * inv * params[OFF_GO + tid] + params[OFF_BEO + tid];
  hh[tid] = hn;
  __syncthreads();
  if (tid < ZDIM){
    const float* W2 = params + OFF_WO2;
    float o = params[OFF_BO2 + tid];
    for (int k = 0; k < 256; ++k) o = fmaf(hh[k], W2[k * 128 + tid], o);
    if (*flag) ((float*)out)[g * 128 + tid] = o;
    else       ((__hip_bfloat16*)out)[g * 128 + tid] = __float2bfloat16(o);
  }
}

extern "C" void kernel_launch(void* const* d_in, const int* in_sizes, int n_in,
                              void* d_out, int out_size, void* d_ws, size_t ws_size,
                              hipStream_t stream){
  // ---- workspace layout ----
  size_t o = 0;
  auto alloc = [&](size_t bytes)->size_t{ size_t r = o; o = (o + bytes + 255) & ~(size_t)255; return r; };
  size_t off_flag   = alloc(4);
  size_t off_deg    = alloc((size_t)N_NODES * 4);
  size_t off_dinv   = alloc((size_t)N_NODES * 4);
  size_t off_rs     = alloc((size_t)(N_NODES + 1) * 4);
  size_t off_fill   = alloc((size_t)N_NODES * 4);
  size_t off_bsum   = alloc((size_t)NSCANBLK * 4);
  size_t off_boff   = alloc((size_t)NSCANBLK * 4);
  size_t off_csrs   = alloc((size_t)(N_EDGES + N_NODES) * 4);
  size_t off_csrw   = alloc((size_t)(N_EDGES + N_NODES) * 4);
  size_t off_params = alloc((size_t)PARAMS_TOTAL * 4);
  size_t off_xbf    = alloc((size_t)N_NODES * HIDDEN * 2);
  size_t off_hbf    = alloc((size_t)N_NODES * HIDDEN * 2);
  size_t off_wt     = alloc((size_t)NLAYERS * HIDDEN * HIDDEN * 2);
  size_t off_pool   = alloc((size_t)NGRAPHS * 256 * 4);
  size_t off_cnt    = alloc((size_t)NGRAPHS * 4);
  if (o > ws_size) return;

  char* ws = (char*)d_ws;
  int*    flag     = (int*)(ws + off_flag);
  int*    deg      = (int*)(ws + off_deg);
  float*  dinv     = (float*)(ws + off_dinv);
  int*    row_start= (int*)(ws + off_rs);
  int*    fill     = (int*)(ws + off_fill);
  int*    bsum     = (int*)(ws + off_bsum);
  int*    boff     = (int*)(ws + off_boff);
  int*    csr_src  = (int*)(ws + off_csrs);
  float*  csr_w    = (float*)(ws + off_csrw);
  float*  params   = (float*)(ws + off_params);
  ushort* x_bf     = (ushort*)(ws + off_xbf);
  ushort* h_bf     = (ushort*)(ws + off_hbf);
  ushort* Wt       = (ushort*)(ws + off_wt);
  float*  pooled   = (float*)(ws + off_pool);
  float*  counts   = (float*)(ws + off_cnt);

  const int* edge_src = (const int*)d_in[1];               // edge_index[0]
  const int* edge_dst = (const int*)d_in[1] + N_EDGES;     // edge_index[1]
  const int* batch    = (const int*)d_in[2];

  // ---- fused dtype detect + param convert + Wt build ----
  PrepArgs pa;
  const int srcIdx[14] = {0,3,4,5,6,8,9,10,11,12,13,14,15,16};
  const int ns[14]     = {150000,768,256,256,256,768,768,768,65536,256,256,256,32768,128};
  const int offs[14]   = {OFF_POS,OFF_WIN,OFF_BIN,OFF_GIN,OFF_BEIN,OFF_CONVB,OFF_GNG,OFF_GNB,
                          OFF_WO1,OFF_BO1,OFF_GO,OFF_BEO,OFF_WO2,OFF_BO2};
  for (int i = 0; i < 14; ++i){ pa.src[i] = d_in[srcIdx[i]]; pa.n[i] = ns[i]; pa.off[i] = offs[i]; }
  pa.win = d_in[3]; pa.convw = d_in[7];
  k_prep<<<512, 256, 0, stream>>>(pa, params, Wt, flag);

  // ---- graph preprocessing ----
  k_init<<<(N_NODES + 255) / 256, 256, 0, stream>>>(deg, fill, pooled, counts);
  k_deg<<<(N_EDGES + 255) / 256, 256, 0, stream>>>(edge_dst, deg);
  k_scan1<<<NSCANBLK, 256, 0, stream>>>(deg, row_start, bsum, dinv);
  k_scan2<<<1, 256, 0, stream>>>(bsum, boff, row_start);
  k_scan3<<<NSCANBLK, 256, 0, stream>>>(deg, boff, row_start);
  k_fill<<<(N_EDGES + N_NODES + 255) / 256, 256, 0, stream>>>(edge_src, edge_dst, row_start, fill,
                                                              dinv, csr_src, csr_w);
  // ---- input projection ----
  k_input_proj<<<N_NODES / 4, 256, 0, stream>>>(params, x_bf);

  // ---- GCN layers ----
  dim3 ggrid(2, (N_NODES + GBM - 1) / GBM);
  for (int l = 0; l < NLAYERS; ++l){
    k_gemm_bf<<<ggrid, 256, 0, stream>>>(x_bf, Wt + l * 65536, h_bf, N_NODES);
    k_agg_norm<<<N_NODES / 4, 256, 0, stream>>>(h_bf, x_bf, row_start, csr_src, csr_w, params, l);
  }

  // ---- pool + head ----
  k_pool<<<(N_NODES + PBLK - 1) / PBLK, 256, 0, stream>>>(x_bf, batch, pooled, counts);
  k_head<<<NGRAPHS, 256, 0, stream>>>(pooled, counts, params, d_out, flag);
}

// Round 7
// 352.707 us; speedup vs baseline: 2.2364x; 1.0500x over previous
//
#include <hip/hip_runtime.h>
#include <hip/hip_bf16.h>

#define N_NODES 50000
#define N_EDGES 300000
#define HIDDEN 256
#define ZDIM 128
#define NLAYERS 3
#define NGRAPHS 16
#define EPS 1e-5f
#define NSCANBLK 196   // ceil(50000/256)

// ---- fp32 param region offsets (floats) ----
#define OFF_POS    0
#define OFF_WIN    150000
#define OFF_BIN    150768
#define OFF_GIN    151024
#define OFF_BEIN   151280
#define OFF_CONVB  348144
#define OFF_GNG    348912
#define OFF_GNB    349680
#define OFF_WO1    350448
#define OFF_BO1    415984
#define OFF_GO     416240
#define OFF_BEO    416496
#define OFF_WO2    416752
#define OFF_BO2    449520
#define PARAMS_TOTAL 449648

typedef __attribute__((ext_vector_type(8))) short short8;
typedef __attribute__((ext_vector_type(4))) float floatx4;

__device__ inline float wave_reduce_sum(float v){
#pragma unroll
  for (int off = 32; off; off >>= 1) v += __shfl_xor(v, off);
  return v;
}

__device__ inline ushort f2bf(float f){
  __hip_bfloat16 t = __float2bfloat16(f);
  return *(ushort*)&t;
}
__device__ inline float bflo(unsigned int u){ return __uint_as_float(u << 16); }
__device__ inline float bfhi(unsigned int u){ return __uint_as_float(u & 0xffff0000u); }

__device__ inline void gload_lds16(const void* g, void* l){
  __builtin_amdgcn_global_load_lds((const __attribute__((address_space(1))) void*)g,
                                   (__attribute__((address_space(3))) void*)l, 16, 0, 0);
}

struct PrepArgs { const void* src[14]; int n[14]; int off[14]; const void* win; const void* convw; };

// fused: per-block dtype detect + param convert (14 tensors) + Wt build (transposed bf16 conv_W)
__global__ __launch_bounds__(256) void k_prep(PrepArgs a, float* __restrict__ params,
                                              ushort* __restrict__ Wt, int* __restrict__ flag){
  __shared__ int sf;
  int tid = threadIdx.x;
  if (tid == 0) sf = 0;
  __syncthreads();
  const unsigned short* w = (const unsigned short*)a.win;
  for (int i = tid; i < 768; i += 256){
    int e = (w[i] >> 7) & 0xff;            // bf16 exponent field
    if (e >= 148) atomicOr(&sf, 1);        // |v|>=2^20: impossible for real bf16 weights
  }
  __syncthreads();
  const bool isf32 = (sf != 0);
  if (blockIdx.x == 0 && tid == 0) *flag = sf;

  int stride = gridDim.x * blockDim.x;
  int t0 = blockIdx.x * blockDim.x + tid;
  for (int s = 0; s < 14; ++s){
    const void* src = a.src[s];
    int n = a.n[s];
    float* dst = params + a.off[s];
    if (isf32){
      const float* f = (const float*)src;
      for (int i = t0; i < n; i += stride) dst[i] = f[i];
    } else {
      const unsigned short* u = (const unsigned short*)src;
      for (int i = t0; i < n; i += stride) dst[i] = bflo(u[i]);
    }
  }
  // Wt[l][n][k] = conv_W[l][k][n] as bf16, read directly from source
  for (int idx = t0; idx < NLAYERS * 65536; idx += stride){
    int l = idx >> 16, rem = idx & 65535, n = rem >> 8, k = rem & 255;
    int si = l * 65536 + k * 256 + n;
    float v = isf32 ? ((const float*)a.convw)[si] : bflo(((const unsigned short*)a.convw)[si]);
    Wt[idx] = f2bf(v);
  }
}

__global__ void k_init(int* __restrict__ deg, int* __restrict__ fill,
                       float* __restrict__ pooled, float* __restrict__ counts){
  int i = blockIdx.x * blockDim.x + threadIdx.x;
  if (i < N_NODES){ deg[i] = 1; fill[i] = 0; }       // self-loop contributes 1
  if (i < NGRAPHS * 256) pooled[i] = 0.f;
  if (i < NGRAPHS) counts[i] = 0.f;
}

__global__ void k_deg(const int* __restrict__ dst, int* __restrict__ deg){
  int e = blockIdx.x * blockDim.x + threadIdx.x;
  if (e < N_EDGES) atomicAdd(&deg[dst[e]], 1);
}

// ---- hierarchical exclusive scan of deg -> row_start (+ fused dinv) ----
__global__ __launch_bounds__(256) void k_scan1(const int* __restrict__ deg, int* __restrict__ row_start,
                                               int* __restrict__ bsum, float* __restrict__ dinv){
  __shared__ int sd[256];
  int tid = threadIdx.x;
  int i = blockIdx.x * 256 + tid;
  int v = (i < N_NODES) ? deg[i] : 0;
  if (i < N_NODES) dinv[i] = rsqrtf((float)v);
  sd[tid] = v;
  __syncthreads();
#pragma unroll
  for (int off = 1; off < 256; off <<= 1){
    int t = (tid >= off) ? sd[tid - off] : 0;
    __syncthreads();
    sd[tid] += t;
    __syncthreads();
  }
  if (i < N_NODES) row_start[i] = sd[tid];
  if (tid == 255) bsum[blockIdx.x] = sd[255];
}

__global__ __launch_bounds__(256) void k_scan2(const int* __restrict__ bsum, int* __restrict__ boff,
                                               int* __restrict__ row_start){
  __shared__ int sd[256];
  int tid = threadIdx.x;
  int v = (tid < NSCANBLK) ? bsum[tid] : 0;
  sd[tid] = v;
  __syncthreads();
#pragma unroll
  for (int off = 1; off < 256; off <<= 1){
    int t = (tid >= off) ? sd[tid - off] : 0;
    __syncthreads();
    sd[tid] += t;
    __syncthreads();
  }
  if (tid < NSCANBLK) boff[tid] = sd[tid] - v;   // exclusive
  if (tid == NSCANBLK - 1) row_start[N_NODES] = sd[tid];
}

__global__ __launch_bounds__(256) void k_scan3(const int* __restrict__ deg, const int* __restrict__ boff,
                                               int* __restrict__ row_start){
  int i = blockIdx.x * 256 + threadIdx.x;
  if (i < N_NODES) row_start[i] = row_start[i] + boff[blockIdx.x] - deg[i];
}

__global__ void k_fill(const int* __restrict__ src, const int* __restrict__ dst,
                       const int* __restrict__ row_start, int* __restrict__ fill,
                       const float* __restrict__ dinv,
                       int* __restrict__ csr_src, float* __restrict__ csr_w){
  int t = blockIdx.x * blockDim.x + threadIdx.x;
  if (t >= N_EDGES + N_NODES) return;
  int s, d;
  if (t < N_EDGES){ s = src[t]; d = dst[t]; }
  else            { s = t - N_EDGES; d = s; }      // self loops
  int pos = row_start[d] + atomicAdd(&fill[d], 1);
  csr_src[pos] = s;
  csr_w[pos] = dinv[s] * dinv[d];
}

// input projection: Linear(3,256) -> ReLU -> GroupNorm(1,256). one wave per node. bf16 out.
__global__ __launch_bounds__(256) void k_input_proj(const float* __restrict__ params,
                                                    ushort* __restrict__ x_bf){
  int lane = threadIdx.x & 63;
  int node = (blockIdx.x << 2) + (threadIdx.x >> 6);
  if (node >= N_NODES) return;
  const float* pos = params + OFF_POS + node * 3;
  float px = pos[0], py = pos[1], pz = pos[2];
  int c = lane * 4;
  const float* w0 = params + OFF_WIN;
  float v[4];
#pragma unroll
  for (int j = 0; j < 4; ++j){
    float t = params[OFF_BIN + c + j];
    t = fmaf(px, w0[c + j], t);
    t = fmaf(py, w0[256 + c + j], t);
    t = fmaf(pz, w0[512 + c + j], t);
    v[j] = fmaxf(t, 0.f);
  }
  float s  = v[0] + v[1] + v[2] + v[3];
  float ss = v[0]*v[0] + v[1]*v[1] + v[2]*v[2] + v[3]*v[3];
  s = wave_reduce_sum(s); ss = wave_reduce_sum(ss);
  float mean = s * (1.f/256.f);
  float var  = ss * (1.f/256.f) - mean * mean;
  float inv  = rsqrtf(var + EPS);
  float4 o;
  o.x = (v[0]-mean)*inv*params[OFF_GIN+c+0] + params[OFF_BEIN+c+0];
  o.y = (v[1]-mean)*inv*params[OFF_GIN+c+1] + params[OFF_BEIN+c+1];
  o.z = (v[2]-mean)*inv*params[OFF_GIN+c+2] + params[OFF_BEIN+c+2];
  o.w = (v[3]-mean)*inv*params[OFF_GIN+c+3] + params[OFF_BEIN+c+3];
  ushort4 ob = { f2bf(o.x), f2bf(o.y), f2bf(o.z), f2bf(o.w) };
  *(ushort4*)(x_bf + node * 256 + c) = ob;
}

// bf16 MFMA GEMM: Cb(Mx256 bf16) = A(Mx256 bf16) @ Wt^T.  Wt is [n][k].
// 128x128 tile, BK=64, async global_load_lds (16B) staging with XOR granule swizzle:
// LDS row r (64 shorts, no padding) granule g holds global granule g^(r&7).
#define GBM 128
__global__ __launch_bounds__(256) void k_gemm_bf(const ushort* __restrict__ A, const ushort* __restrict__ Bt,
                                                 ushort* __restrict__ Cb, int M){
  __shared__ __align__(16) ushort Sh[2 * GBM * 64];   // As | Bs
  ushort* As = Sh;
  ushort* Bs = Sh + GBM * 64;
  int tid = threadIdx.x;
  int wave = tid >> 6, lane = tid & 63;
  int wr = wave >> 1, wc = wave & 1;
  int row0 = blockIdx.y * GBM;
  int col0 = blockIdx.x * GBM;
  int q = lane >> 4, l15 = lane & 15;
  int srow = lane >> 3;      // row within 8-row staging group
  int sg   = lane & 7;       // destination granule (HW: lane*16B contiguous)
  floatx4 acc[4][4] = {};
  for (int k0 = 0; k0 < 256; k0 += 64){
    __syncthreads();
#pragma unroll
    for (int t = 0; t < 4; ++t){
      int rg = wave * 4 + t;               // 8-row group 0..15
      int r  = rg * 8 + srow;              // tile row 0..127
      int gs = sg ^ (r & 7);               // swizzled SOURCE granule
      const ushort* ga = A  + (size_t)(row0 + r) * 256 + k0 + gs * 8;  // tail rows: valid ws memory, never stored
      const ushort* gb = Bt + (size_t)(col0 + r) * 256 + k0 + gs * 8;
      gload_lds16(ga, As + rg * 512);
      gload_lds16(gb, Bs + rg * 512);
    }
    __syncthreads();
#pragma unroll
    for (int kk = 0; kk < 64; kk += 32){
      short8 af[4], bfr[4];
#pragma unroll
      for (int i = 0; i < 4; ++i){
        int R = wr * 64 + i * 16 + l15;
        int bg = (kk >> 3) + q;                       // logical granule 0..7
        af[i] = *(const short8*)(As + R * 64 + ((bg ^ (R & 7)) << 3));
      }
#pragma unroll
      for (int j = 0; j < 4; ++j){
        int C = wc * 64 + j * 16 + l15;
        int bg = (kk >> 3) + q;
        bfr[j] = *(const short8*)(Bs + C * 64 + ((bg ^ (C & 7)) << 3));
      }
#pragma unroll
      for (int i = 0; i < 4; ++i)
#pragma unroll
        for (int j = 0; j < 4; ++j)
          acc[i][j] = __builtin_amdgcn_mfma_f32_16x16x32_bf16(af[i], bfr[j], acc[i][j], 0, 0, 0);
    }
  }
#pragma unroll
  for (int i = 0; i < 4; ++i){
#pragma unroll
    for (int r = 0; r < 4; ++r){
      int row = row0 + wr * 64 + i * 16 + q * 4 + r;
      if (row < M){
#pragma unroll
        for (int j = 0; j < 4; ++j){
          int col = col0 + wc * 64 + j * 16 + l15;
          Cb[row * 256 + col] = f2bf(acc[i][j][r]);
        }
      }
    }
  }
}

// aggregate over CSR (bf16 h) + bias + GroupNorm + ReLU + residual (bf16 x, in-place).
__global__ __launch_bounds__(256) void k_agg_norm(const ushort* __restrict__ hb, ushort* __restrict__ x_bf,
    const int* __restrict__ row_start, const int* __restrict__ csr_src, const float* __restrict__ csr_w,
    const float* __restrict__ params, int layer){
  int lane = threadIdx.x & 63;
  int node = (blockIdx.x << 2) + (threadIdx.x >> 6);
  if (node >= N_NODES) return;
  int c = lane * 4;
  float a0 = 0.f, a1 = 0.f, a2 = 0.f, a3 = 0.f;
  int p0 = row_start[node], p1 = row_start[node + 1];
  int p = p0;
  for (; p + 4 <= p1; p += 4){
    int s0 = csr_src[p],     s1 = csr_src[p + 1];
    int s2 = csr_src[p + 2], s3 = csr_src[p + 3];
    float w0 = csr_w[p],     w1 = csr_w[p + 1];
    float w2 = csr_w[p + 2], w3 = csr_w[p + 3];
    uint2 v0 = *(const uint2*)(hb + (size_t)s0 * 256 + c);
    uint2 v1 = *(const uint2*)(hb + (size_t)s1 * 256 + c);
    uint2 v2 = *(const uint2*)(hb + (size_t)s2 * 256 + c);
    uint2 v3 = *(const uint2*)(hb + (size_t)s3 * 256 + c);
    a0 = fmaf(w0, bflo(v0.x), a0); a1 = fmaf(w0, bfhi(v0.x), a1);
    a2 = fmaf(w0, bflo(v0.y), a2); a3 = fmaf(w0, bfhi(v0.y), a3);
    a0 = fmaf(w1, bflo(v1.x), a0); a1 = fmaf(w1, bfhi(v1.x), a1);
    a2 = fmaf(w1, bflo(v1.y), a2); a3 = fmaf(w1, bfhi(v1.y), a3);
    a0 = fmaf(w2, bflo(v2.x), a0); a1 = fmaf(w2, bfhi(v2.x), a1);
    a2 = fmaf(w2, bflo(v2.y), a2); a3 = fmaf(w2, bfhi(v2.y), a3);
    a0 = fmaf(w3, bflo(v3.x), a0); a1 = fmaf(w3, bfhi(v3.x), a1);
    a2 = fmaf(w3, bflo(v3.y), a2); a3 = fmaf(w3, bfhi(v3.y), a3);
  }
  for (; p < p1; ++p){
    int s0 = csr_src[p];
    float w0 = csr_w[p];
    uint2 v0 = *(const uint2*)(hb + (size_t)s0 * 256 + c);
    a0 = fmaf(w0, bflo(v0.x), a0); a1 = fmaf(w0, bfhi(v0.x), a1);
    a2 = fmaf(w0, bflo(v0.y), a2); a3 = fmaf(w0, bfhi(v0.y), a3);
  }
  const float* cb = params + OFF_CONVB + layer * 256;
  float v[4] = { a0 + cb[c], a1 + cb[c+1], a2 + cb[c+2], a3 + cb[c+3] };
  float s  = v[0] + v[1] + v[2] + v[3];
  float ss = v[0]*v[0] + v[1]*v[1] + v[2]*v[2] + v[3]*v[3];
  s = wave_reduce_sum(s); ss = wave_reduce_sum(ss);
  float mean = s * (1.f/256.f);
  float var  = ss * (1.f/256.f) - mean * mean;
  float inv  = rsqrtf(var + EPS);
  const float* g = params + OFF_GNG + layer * 256;
  const float* b = params + OFF_GNB + layer * 256;
  uint2 xo = *(uint2*)(x_bf + (size_t)node * 256 + c);
  float o0 = fmaxf((v[0]-mean)*inv*g[c+0] + b[c+0], 0.f) + bflo(xo.x);
  float o1 = fmaxf((v[1]-mean)*inv*g[c+1] + b[c+1], 0.f) + bfhi(xo.x);
  float o2 = fmaxf((v[2]-mean)*inv*g[c+2] + b[c+2], 0.f) + bflo(xo.y);
  float o3 = fmaxf((v[3]-mean)*inv*g[c+3] + b[c+3], 0.f) + bfhi(xo.y);
  ushort4 ob = { f2bf(o0), f2bf(o1), f2bf(o2), f2bf(o3) };
  *(ushort4*)(x_bf + (size_t)node * 256 + c) = ob;
}

// global mean pool: 196 blocks x 256 nodes; wave owns 64 nodes, 8-deep load unroll;
// LDS [16][256] block accumulator; one global-atomic row flush per graph present in block.
#define PBLK 256
__global__ __launch_bounds__(256) void k_pool(const ushort* __restrict__ x_bf, const int* __restrict__ batch,
                                              float* __restrict__ pooled, float* __restrict__ counts){
  __shared__ float lacc[NGRAPHS][256];
  __shared__ float lcnt[NGRAPHS];
  int tid = threadIdx.x;
  int wave = tid >> 6, lane = tid & 63;
  int c = lane * 4;
#pragma unroll
  for (int g = 0; g < NGRAPHS; ++g) lacc[g][tid] = 0.f;
  if (tid < NGRAPHS) lcnt[tid] = 0.f;
  __syncthreads();

  int n0 = blockIdx.x * PBLK + wave * 64;
  if (n0 < N_NODES){
    int n1 = min(n0 + 64, N_NODES);
    int b0 = batch[n0], b1 = batch[n1 - 1];
    float a0 = 0.f, a1 = 0.f, a2 = 0.f, a3 = 0.f;
    if (b0 == b1){                            // wave-uniform fast path
      int i = n0;
      for (; i + 8 <= n1; i += 8){
        uint2 v[8];
#pragma unroll
        for (int j = 0; j < 8; ++j) v[j] = *(const uint2*)(x_bf + (size_t)(i + j) * 256 + c);
#pragma unroll
        for (int j = 0; j < 8; ++j){
          a0 += bflo(v[j].x); a1 += bfhi(v[j].x);
          a2 += bflo(v[j].y); a3 += bfhi(v[j].y);
        }
      }
      for (; i < n1; ++i){
        uint2 v = *(const uint2*)(x_bf + (size_t)i * 256 + c);
        a0 += bflo(v.x); a1 += bfhi(v.x); a2 += bflo(v.y); a3 += bfhi(v.y);
      }
      atomicAdd(&lacc[b0][c + 0], a0); atomicAdd(&lacc[b0][c + 1], a1);
      atomicAdd(&lacc[b0][c + 2], a2); atomicAdd(&lacc[b0][c + 3], a3);
      if (lane == 0) atomicAdd(&lcnt[b0], (float)(n1 - n0));
    } else {                                  // boundary wave (<=15 per launch)
      int cur = b0, cnt = 0;
      for (int i = n0; i < n1; ++i){
        int g = batch[i];
        if (g != cur){
          atomicAdd(&lacc[cur][c + 0], a0); atomicAdd(&lacc[cur][c + 1], a1);
          atomicAdd(&lacc[cur][c + 2], a2); atomicAdd(&lacc[cur][c + 3], a3);
          if (lane == 0) atomicAdd(&lcnt[cur], (float)cnt);
          a0 = a1 = a2 = a3 = 0.f; cnt = 0; cur = g;
        }
        uint2 v = *(const uint2*)(x_bf + (size_t)i * 256 + c);
        a0 += bflo(v.x); a1 += bfhi(v.x); a2 += bflo(v.y); a3 += bfhi(v.y);
        cnt++;
      }
      atomicAdd(&lacc[cur][c + 0], a0); atomicAdd(&lacc[cur][c + 1], a1);
      atomicAdd(&lacc[cur][c + 2], a2); atomicAdd(&lacc[cur][c + 3], a3);
      if (lane == 0) atomicAdd(&lcnt[cur], (float)cnt);
    }
  }
  __syncthreads();

  int base = blockIdx.x * PBLK;
  if (base < N_NODES){
    int gmin = batch[base];
    int gmax = batch[min(base + PBLK, N_NODES) - 1];
    for (int g = gmin; g <= gmax; ++g){
      float v = lacc[g][tid];
      if (v != 0.f) atomicAdd(&pooled[g * 256 + tid], v);
      if (tid == 0 && lcnt[g] > 0.f) atomicAdd(&counts[g], lcnt[g]);
    }
  }
}

__global__ __launch_bounds__(256) void k_head(const float* __restrict__ pooled, const float* __restrict__ counts,
    const float* __restrict__ params, void* __restrict__ out, const int* __restrict__ flag){
  __shared__ float m[256];
  __shared__ float hh[256];
  __shared__ float red[2][4];
  int g = blockIdx.x, tid = threadIdx.x;
  float cnt = fmaxf(counts[g], 1.f);
  m[tid] = pooled[g * 256 + tid] / cnt;
  __syncthreads();
  const float* W1 = params + OFF_WO1;
  float acc = params[OFF_BO1 + tid];
  for (int k = 0; k < 256; ++k) acc = fmaf(m[k], W1[k * 256 + tid], acc);
  acc = fmaxf(acc, 0.f);
  float s = wave_reduce_sum(acc), ss = wave_reduce_sum(acc * acc);
  int wv = tid >> 6, lane = tid & 63;
  if (lane == 0){ red[0][wv] = s; red[1][wv] = ss; }
  __syncthreads();
  float S  = red[0][0] + red[0][1] + red[0][2] + red[0][3];
  float SS = red[1][0] + red[1][1] + red[1][2] + red[1][3];
  float mean = S * (1.f/256.f);
  float var  = SS * (1.f/256.f) - mean * mean;
  float inv  = rsqrtf(var + EPS);
  float hn = (acc - mean) * inv * params[OFF_GO + tid] + params[OFF_BEO + tid];
  hh[tid] = hn;
  __syncthreads();
  if (tid < ZDIM){
    const float* W2 = params + OFF_WO2;
    float o = params[OFF_BO2 + tid];
    for (int k = 0; k < 256; ++k) o = fmaf(hh[k], W2[k * 128 + tid], o);
    if (*flag) ((float*)out)[g * 128 + tid] = o;
    else       ((__hip_bfloat16*)out)[g * 128 + tid] = __float2bfloat16(o);
  }
}

extern "C" void kernel_launch(void* const* d_in, const int* in_sizes, int n_in,
                              void* d_out, int out_size, void* d_ws, size_t ws_size,
                              hipStream_t stream){
  // ---- workspace layout ----
  size_t o = 0;
  auto alloc = [&](size_t bytes)->size_t{ size_t r = o; o = (o + bytes + 255) & ~(size_t)255; return r; };
  size_t off_flag   = alloc(4);
  size_t off_deg    = alloc((size_t)N_NODES * 4);
  size_t off_dinv   = alloc((size_t)N_NODES * 4);
  size_t off_rs     = alloc((size_t)(N_NODES + 1) * 4);
  size_t off_fill   = alloc((size_t)N_NODES * 4);
  size_t off_bsum   = alloc((size_t)NSCANBLK * 4);
  size_t off_boff   = alloc((size_t)NSCANBLK * 4);
  size_t off_csrs   = alloc((size_t)(N_EDGES + N_NODES) * 4);
  size_t off_csrw   = alloc((size_t)(N_EDGES + N_NODES) * 4);
  size_t off_params = alloc((size_t)PARAMS_TOTAL * 4);
  size_t off_xbf    = alloc((size_t)N_NODES * HIDDEN * 2);
  size_t off_hbf    = alloc((size_t)N_NODES * HIDDEN * 2);
  size_t off_wt     = alloc((size_t)NLAYERS * HIDDEN * HIDDEN * 2);
  size_t off_pool   = alloc((size_t)NGRAPHS * 256 * 4);
  size_t off_cnt    = alloc((size_t)NGRAPHS * 4);
  if (o > ws_size) return;

  char* ws = (char*)d_ws;
  int*    flag     = (int*)(ws + off_flag);
  int*    deg      = (int*)(ws + off_deg);
  float*  dinv     = (float*)(ws + off_dinv);
  int*    row_start= (int*)(ws + off_rs);
  int*    fill     = (int*)(ws + off_fill);
  int*    bsum     = (int*)(ws + off_bsum);
  int*    boff     = (int*)(ws + off_boff);
  int*    csr_src  = (int*)(ws + off_csrs);
  float*  csr_w    = (float*)(ws + off_csrw);
  float*  params   = (float*)(ws + off_params);
  ushort* x_bf     = (ushort*)(ws + off_xbf);
  ushort* h_bf     = (ushort*)(ws + off_hbf);
  ushort* Wt       = (ushort*)(ws + off_wt);
  float*  pooled   = (float*)(ws + off_pool);
  float*  counts   = (float*)(ws + off_cnt);

  const int* edge_src = (const int*)d_in[1];               // edge_index[0]
  const int* edge_dst = (const int*)d_in[1] + N_EDGES;     // edge_index[1]
  const int* batch    = (const int*)d_in[2];

  // ---- fused dtype detect + param convert + Wt build ----
  PrepArgs pa;
  const int srcIdx[14] = {0,3,4,5,6,8,9,10,11,12,13,14,15,16};
  const int ns[14]     = {150000,768,256,256,256,768,768,768,65536,256,256,256,32768,128};
  const int offs[14]   = {OFF_POS,OFF_WIN,OFF_BIN,OFF_GIN,OFF_BEIN,OFF_CONVB,OFF_GNG,OFF_GNB,
                          OFF_WO1,OFF_BO1,OFF_GO,OFF_BEO,OFF_WO2,OFF_BO2};
  for (int i = 0; i < 14; ++i){ pa.src[i] = d_in[srcIdx[i]]; pa.n[i] = ns[i]; pa.off[i] = offs[i]; }
  pa.win = d_in[3]; pa.convw = d_in[7];
  k_prep<<<512, 256, 0, stream>>>(pa, params, Wt, flag);

  // ---- graph preprocessing ----
  k_init<<<(N_NODES + 255) / 256, 256, 0, stream>>>(deg, fill, pooled, counts);
  k_deg<<<(N_EDGES + 255) / 256, 256, 0, stream>>>(edge_dst, deg);
  k_scan1<<<NSCANBLK, 256, 0, stream>>>(deg, row_start, bsum, dinv);
  k_scan2<<<1, 256, 0, stream>>>(bsum, boff, row_start);
  k_scan3<<<NSCANBLK, 256, 0, stream>>>(deg, boff, row_start);
  k_fill<<<(N_EDGES + N_NODES + 255) / 256, 256, 0, stream>>>(edge_src, edge_dst, row_start, fill,
                                                              dinv, csr_src, csr_w);
  // ---- input projection ----
  k_input_proj<<<N_NODES / 4, 256, 0, stream>>>(params, x_bf);

  // ---- GCN layers ----
  dim3 ggrid(2, (N_NODES + GBM - 1) / GBM);
  for (int l = 0; l < NLAYERS; ++l){
    k_gemm_bf<<<ggrid, 256, 0, stream>>>(x_bf, Wt + l * 65536, h_bf, N_NODES);
    k_agg_norm<<<N_NODES / 4, 256, 0, stream>>>(h_bf, x_bf, row_start, csr_src, csr_w, params, l);
  }

  // ---- pool + head ----
  k_pool<<<(N_NODES + PBLK - 1) / PBLK, 256, 0, stream>>>(x_bf, batch, pooled, counts);
  k_head<<<NGRAPHS, 256, 0, stream>>>(pooled, counts, params, d_out, flag);
}